// Round 9
// baseline (453.827 us; speedup 1.0000x reference)
//
#include <hip/hip_runtime.h>
#include <math.h>

// SpectralAttention gfx950 — round 13: k_gemm_qkv staging -> global_load_lds.
// R12 verified: total 439us, flash 148.7 (Mfma 40 / VALU 36 / conflicts 0 —
// near pipe saturation).  Remaining big item: k_gemm_qkv (~110-130us est),
// which stages via uint4 loads + byte-perm write_split (the 646-TF pattern;
// guide m151).  Fix: store split-fp16 data as TWO PLANAR fp16 buffers
// pre-tiled in MFMA-frag order [row/16][k/32][lane64][8halves], so staging
// becomes 8x global_load_lds(16B)/wave/K-step (m97 2-barrier structure,
// 874-912 TF).  LDS contents bit-identical to R12 -> MFMA math unchanged.
// Converted: k_gemm_qkv + prep_wpl3 (wq/wk/wv) + prep_xpl (x).  Flash, FFT,
// gemm_out, prep_w(wo), norm: unchanged from the passing R12 build.
// B=2, T=2048, C=1024, H=16, HD=64.
//
// Packed split format (u32): lo16 = fp16(v) ["hi" part], hi16 = fp16((v-hi)*2048).
// v = hi + lo/2048 to ~2^-22 rel.  3-term MFMA: D = Ah*Bh + (Ah*Bl + Al*Bh)/2048.
//
// ws layout (floats) with region reuse:
//   [0,  4M)  qT -> qpk -> wopk     [4M, 8M)  kT -> kpk    [8M, 12M) vT -> vpk
//   [12M,16M) w-planes(12MB) -> qipk   [16M,20M) kipk
//   [20M,24M) x-planes(16MB) -> attpk  24M: tables
// total 96 MB + 16 KB

typedef _Float16 half8 __attribute__((ext_vector_type(8)));
typedef float f32x4 __attribute__((ext_vector_type(4)));
#define MFMA16 __builtin_amdgcn_mfma_f32_16x16x32_f16

#define GLOAD16(g, l) __builtin_amdgcn_global_load_lds( \
    (const __attribute__((address_space(1))) void*)(g), \
    (__attribute__((address_space(3))) void*)(l), 16, 0, 0)

__device__ inline unsigned pack_split(float v) {
    _Float16 h = (_Float16)v;
    float r = (v - (float)h) * 2048.0f;
    _Float16 l = (_Float16)r;
    union { _Float16 f; unsigned short u; } a, b;
    a.f = h; b.f = l;
    return (unsigned)a.u | ((unsigned)b.u << 16);
}
__device__ inline void split2(float v, _Float16& h, _Float16& l) {
    h = (_Float16)v;
    l = (_Float16)((v - (float)h) * 2048.0f);
}
__device__ inline _Float16 lo16(unsigned u) {
    union { unsigned short s; _Float16 f; } x; x.s = (unsigned short)(u & 0xffffu); return x.f;
}
__device__ inline _Float16 hi16(unsigned u) {
    union { unsigned short s; _Float16 f; } x; x.s = (unsigned short)(u >> 16); return x.f;
}

// split 8 packed u32 into hi-half8 / lo-half8 via byte-perms, store as 2 b128
__device__ inline void write_split(_Float16* dh, _Float16* dl, uint4 u0, uint4 u1) {
    uint4 lo, hi;
    lo.x = __builtin_amdgcn_perm(u0.y, u0.x, 0x05040100u);
    lo.y = __builtin_amdgcn_perm(u0.w, u0.z, 0x05040100u);
    lo.z = __builtin_amdgcn_perm(u1.y, u1.x, 0x05040100u);
    lo.w = __builtin_amdgcn_perm(u1.w, u1.z, 0x05040100u);
    hi.x = __builtin_amdgcn_perm(u0.y, u0.x, 0x07060302u);
    hi.y = __builtin_amdgcn_perm(u0.w, u0.z, 0x07060302u);
    hi.z = __builtin_amdgcn_perm(u1.y, u1.x, 0x07060302u);
    hi.w = __builtin_amdgcn_perm(u1.w, u1.z, 0x07060302u);
    *(uint4*)dh = lo;
    *(uint4*)dl = hi;
}

// ---------------------------------------------------------------- init tables
__global__ __launch_bounds__(256) void k_init_tables(
    float2* __restrict__ tw, float2* __restrict__ filt,
    const float* __restrict__ fd, const float* __restrict__ alpha,
    const float* __restrict__ fas)
{
    int i = blockIdx.x * 256 + threadIdx.x;
    double aa = (double)alpha[0] + (double)fas[0] * ((double)fd[0] - 1.5);
    if (i < 1024) {
        double ang = -2.0 * 3.14159265358979323846 * (double)i / 2048.0;
        double s, c;
        sincos(ang, &s, &c);
        tw[i] = make_float2((float)c, (float)s);
    }
    if (i < 2048) {
        double fr = (i < 1024) ? (double)i / 2048.0 : ((double)i - 2048.0) / 2048.0;
        double ph = aa * atan(log(fabs(fr) + 1e-10));
        double s, c;
        sincos(ph, &s, &c);
        filt[i] = make_float2((float)c, (float)s);
    }
}

// ---------------------- prep: W^T -> planar hi/lo planes, MFMA-tiled (x3)
// Plane layout (halves): [c/16][k/32][lane=64][j=8], lane = (c&15)+16*((k>>3)&3),
// j = k&7.  Per mat: hi plane 1M halves, lo plane 1M halves (4MB total).
__global__ __launch_bounds__(256) void k_prep_wpl3(
    const float* __restrict__ wq, const float* __restrict__ wk,
    const float* __restrict__ wv, _Float16* __restrict__ wpl)
{
    __shared__ float tile[64][65];
    const int z = blockIdx.z;
    const float* W = (z == 0) ? wq : (z == 1) ? wk : wv;
    _Float16* Whi = wpl + (size_t)z * 2097152;
    _Float16* Wlo = Whi + 1048576;
    const int kb = blockIdx.x * 64, cb = blockIdx.y * 64;
    const int t = threadIdx.x, r = t >> 4, c4 = (t & 15) * 4;
#pragma unroll
    for (int i = 0; i < 4; ++i) {
        int row = r + 16 * i;
        float4 v = *(const float4*)&W[(size_t)(kb + row) * 1024 + cb + c4];
        tile[row][c4 + 0] = v.x; tile[row][c4 + 1] = v.y;
        tile[row][c4 + 2] = v.z; tile[row][c4 + 3] = v.w;
    }
    __syncthreads();
#pragma unroll
    for (int h = 0; h < 2; ++h) {
        int idx = t + h * 256;
        int lane = idx & 63, kt2 = (idx >> 6) & 1, ct = idx >> 7;
        int cl = ct * 16 + (lane & 15);
        int kl = kt2 * 32 + ((lane >> 4) * 8);
        half8 hv, lv;
#pragma unroll
        for (int j = 0; j < 8; ++j) {
            _Float16 hh, ll;
            split2(tile[kl + j][cl], hh, ll);
            hv[j] = hh; lv[j] = ll;
        }
        size_t u = ((size_t)((cb >> 4) + ct) * 32 + (kb >> 5) + kt2) * 64 + lane;
        *(half8*)&Whi[u * 8] = hv;
        *(half8*)&Wlo[u * 8] = lv;
    }
}

// ---------------------- prep: x -> planar hi/lo planes, MFMA-tiled
// Plane (halves): [n/16][c/32][lane=64][j=8], lane=(n&15)+16*((c>>3)&3), j=c&7.
// xhi 4M halves, xlo 4M halves (16MB total).
__global__ __launch_bounds__(256) void k_prep_xpl(
    const float* __restrict__ x, _Float16* __restrict__ xpl)
{
    __shared__ float tile[64][65];
    _Float16* Xhi = xpl;
    _Float16* Xlo = xpl + 4194304;
    const int nb = blockIdx.x * 64, cb = blockIdx.y * 64;
    const int t = threadIdx.x, r = t >> 4, c4 = (t & 15) * 4;
#pragma unroll
    for (int i = 0; i < 4; ++i) {
        int row = r + 16 * i;
        float4 v = *(const float4*)&x[(size_t)(nb + row) * 1024 + cb + c4];
        tile[row][c4 + 0] = v.x; tile[row][c4 + 1] = v.y;
        tile[row][c4 + 2] = v.z; tile[row][c4 + 3] = v.w;
    }
    __syncthreads();
#pragma unroll
    for (int h = 0; h < 2; ++h) {
        int idx = t + h * 256;
        int lane = idx & 63, ct2 = (idx >> 6) & 1, ntl = (idx >> 7) & 3;
        int nl = ntl * 16 + (lane & 15);
        int cl = ct2 * 32 + ((lane >> 4) * 8);
        half8 hv, lv;
#pragma unroll
        for (int j = 0; j < 8; ++j) {
            _Float16 hh, ll;
            split2(tile[nl][cl + j], hh, ll);
            hv[j] = hh; lv[j] = ll;
        }
        size_t u = ((size_t)((nb >> 4) + ntl) * 32 + (cb >> 5) + ct2) * 64 + lane;
        *(half8*)&Xhi[u * 8] = hv;
        *(half8*)&Xlo[u * 8] = lv;
    }
}

// ------------------------------------------------------- prep: W^T (packed, wo)
__global__ __launch_bounds__(256) void k_prep_w(
    const float* __restrict__ W, unsigned* __restrict__ Wpk)
{
    __shared__ float tile[64][65];
    const int kb = blockIdx.x * 64, cb = blockIdx.y * 64;
    const int t = threadIdx.x, r = t >> 4, c4 = (t & 15) * 4;
#pragma unroll
    for (int i = 0; i < 4; ++i) {
        int row = r + 16 * i;
        float4 v = *(const float4*)&W[(size_t)(kb + row) * 1024 + cb + c4];
        tile[row][c4 + 0] = v.x; tile[row][c4 + 1] = v.y;
        tile[row][c4 + 2] = v.z; tile[row][c4 + 3] = v.w;
    }
    __syncthreads();
#pragma unroll
    for (int i = 0; i < 4; ++i) {
        int crow = r + 16 * i;
        uint4 o;
        o.x = pack_split(tile[c4 + 0][crow]);
        o.y = pack_split(tile[c4 + 1][crow]);
        o.z = pack_split(tile[c4 + 2][crow]);
        o.w = pack_split(tile[c4 + 3][crow]);
        *(uint4*)&Wpk[(size_t)(cb + crow) * 1024 + kb + c4] = o;
    }
}

// --------------------------------------------------- QKV GEMM (MFMA f16-split)
// R13: staging via global_load_lds from planar pre-tiled planes (m97 2-barrier
// structure).  LDS layout identical to R12 -> MFMA/epilogue unchanged.
__global__ __launch_bounds__(256) void k_gemm_qkv(
    const _Float16* __restrict__ xpl, const _Float16* __restrict__ wpl,
    const float* __restrict__ bq, const float* __restrict__ bk,
    const float* __restrict__ bv,
    float* __restrict__ qT, float* __restrict__ kT, float* __restrict__ vT)
{
    __shared__ __align__(16) _Float16 Ab[8][2][64][8];   // 16 KB
    __shared__ __align__(16) _Float16 Bb[8][2][64][8];   // 16 KB
    const int tid = threadIdx.x;
    const int mat = blockIdx.z;
    const _Float16* Ahi = wpl + (size_t)mat * 2097152;
    const _Float16* Alo = Ahi + 1048576;
    const _Float16* Bhi = xpl;
    const _Float16* Blo = xpl + 4194304;
    const float* bias = (mat == 0) ? bq : (mat == 1) ? bk : bv;
    float* outp       = (mat == 0) ? qT : (mat == 1) ? kT : vT;
    const int m0 = blockIdx.x * 128, n0 = blockIdx.y * 128;
    const int w = tid >> 6, lane = tid & 63, quad = lane >> 4, l15 = lane & 15;
    const int wm = (w & 1) * 4, wn = (w >> 1) * 4;

    // wave w stages segments mt/nt = 2w, 2w+1 (4 waves cover 0..7)
    const int s0 = 2 * w, s1 = 2 * w + 1;
    const size_t aT0 = (size_t)((m0 >> 4) + s0) * 32;   // tile-row base (16B rows)
    const size_t aT1 = aT0 + 32;
    const size_t bT0 = (size_t)((n0 >> 4) + s0) * 32;
    const size_t bT1 = bT0 + 32;
    const int ln8 = lane * 8;

    f32x4 acc1[4][4], acc2[4][4];
    const f32x4 z4 = {0.f, 0.f, 0.f, 0.f};
#pragma unroll
    for (int i = 0; i < 4; ++i)
#pragma unroll
        for (int j = 0; j < 4; ++j) { acc1[i][j] = z4; acc2[i][j] = z4; }

    for (int kt = 0; kt < 32; ++kt) {
        __syncthreads();
        {
            size_t oA0 = (aT0 + kt) * 512 + ln8;
            size_t oA1 = (aT1 + kt) * 512 + ln8;
            size_t oB0 = (bT0 + kt) * 512 + ln8;
            size_t oB1 = (bT1 + kt) * 512 + ln8;
            GLOAD16(Ahi + oA0, &Ab[s0][0][0][0]);
            GLOAD16(Alo + oA0, &Ab[s0][1][0][0]);
            GLOAD16(Ahi + oA1, &Ab[s1][0][0][0]);
            GLOAD16(Alo + oA1, &Ab[s1][1][0][0]);
            GLOAD16(Bhi + oB0, &Bb[s0][0][0][0]);
            GLOAD16(Blo + oB0, &Bb[s0][1][0][0]);
            GLOAD16(Bhi + oB1, &Bb[s1][0][0][0]);
            GLOAD16(Blo + oB1, &Bb[s1][1][0][0]);
        }
        __syncthreads();   // compiler drains vmcnt before barrier
        half8 ah[4], al[4];
#pragma unroll
        for (int mt = 0; mt < 4; ++mt) {
            ah[mt] = *(half8*)&Ab[wm + mt][0][lane][0];
            al[mt] = *(half8*)&Ab[wm + mt][1][lane][0];
        }
#pragma unroll
        for (int nt = 0; nt < 4; ++nt) {
            half8 bh = *(half8*)&Bb[wn + nt][0][lane][0];
            half8 bl = *(half8*)&Bb[wn + nt][1][lane][0];
#pragma unroll
            for (int mt = 0; mt < 4; ++mt) {
                acc1[mt][nt] = MFMA16(ah[mt], bh, acc1[mt][nt], 0, 0, 0);
                acc2[mt][nt] = MFMA16(ah[mt], bl, acc2[mt][nt], 0, 0, 0);
                acc2[mt][nt] = MFMA16(al[mt], bh, acc2[mt][nt], 0, 0, 0);
            }
        }
    }
    const int b_ = n0 >> 11, t0 = n0 & 2047;
#pragma unroll
    for (int mt = 0; mt < 4; ++mt) {
#pragma unroll
        for (int r_ = 0; r_ < 4; ++r_) {
            int m = m0 + (wm + mt) * 16 + quad * 4 + r_;
            float bs = bias[m];
            float* orow = &outp[(size_t)(b_ * 1024 + m) * 2048 + t0];
#pragma unroll
            for (int nt = 0; nt < 4; ++nt) {
                float val = acc1[mt][nt][r_] + acc2[mt][nt][r_] * (1.f / 2048.f) + bs;
                orow[(wn + nt) * 16 + l15] = val;
            }
        }
    }
}

// ------------------------------------------------------------- FFT + filter
// Real-FFT pairing: rows (2p, 2p+1) real -> one complex FFT, Hermitian split.
__global__ __launch_bounds__(256) void k_fft_filter(
    float* __restrict__ qT, float* __restrict__ kT, float* __restrict__ vT,
    float* __restrict__ qiT, float* __restrict__ kiT,
    const float2* __restrict__ tw, const float2* __restrict__ filt)
{
    __shared__ float2 sf[2048];
    const int bid = blockIdx.x;          // 0..3071
    const int mat = bid >> 10;
    const int pair = bid & 1023;
    const int seq0 = pair * 2, seq1 = seq0 + 1;
    float* base = (mat == 0) ? qT : (mat == 1) ? kT : vT;
    float* src0 = base + (size_t)seq0 * 2048;
    float* src1 = base + (size_t)seq1 * 2048;
    const int tid = threadIdx.x;

    for (int i = tid; i < 2048; i += 256) {
        int j = (int)(__brev((unsigned)i) >> 21);
        sf[j] = make_float2(src0[i], src1[i]);
    }
    __syncthreads();
    for (int st = 1; st <= 11; ++st) {
        const int half = 1 << (st - 1);
        const int shift = 11 - st;
        for (int u = tid; u < 1024; u += 256) {
            int pos = u & (half - 1);
            int bi = 2 * u - pos;
            float2 w = tw[pos << shift];
            float2 a = sf[bi], b = sf[bi + half];
            float tr = w.x * b.x - w.y * b.y;
            float ti = w.x * b.y + w.y * b.x;
            sf[bi]        = make_float2(a.x + tr, a.y + ti);
            sf[bi + half] = make_float2(a.x - tr, a.y - ti);
        }
        __syncthreads();
    }
    unsigned* dr0 = (unsigned*)src0;
    unsigned* dr1 = (unsigned*)src1;
    unsigned* di0 = (mat == 0) ? (unsigned*)(qiT + (size_t)seq0 * 2048)
                               : (unsigned*)(kiT + (size_t)seq0 * 2048);
    unsigned* di1 = (mat == 0) ? (unsigned*)(qiT + (size_t)seq1 * 2048)
                               : (unsigned*)(kiT + (size_t)seq1 * 2048);
    for (int i = tid; i < 2048; i += 256) {
        float2 z  = sf[i];
        float2 zm = sf[(2048 - i) & 2047];
        float Are = 0.5f * (z.x + zm.x), Aim = 0.5f * (z.y - zm.y);
        float Bre = 0.5f * (z.y + zm.y), Bim = 0.5f * (zm.x - z.x);
        float2 f = filt[i];
        float re0 = Are * f.x - Aim * f.y, im0 = Are * f.y + Aim * f.x;
        float re1 = Bre * f.x - Bim * f.y, im1 = Bre * f.y + Bim * f.x;
        if (mat == 0) {
            dr0[i] = pack_split(0.125f * re0); di0[i] = pack_split(0.125f * im0);
            dr1[i] = pack_split(0.125f * re1); di1[i] = pack_split(0.125f * im1);
        } else if (mat == 1) {
            dr0[i] = pack_split(re0); di0[i] = pack_split(-im0);
            dr1[i] = pack_split(re1); di1[i] = pack_split(-im1);
        } else {
            dr0[i] = pack_split(re0);
            dr1[i] = pack_split(re1);
        }
    }
}

// ------------------------------------------------------------- flash (MFMA f16)
// R12 structure (unchanged): 256 blocks x 512 thr (8 waves); wave owns 32
// rows (2 row-groups); s-step 64; dbuf K/V, ONE barrier/iter; S^T=MFMA(K,Q);
// per-lane softmax + defer-max(THR=8); O^T=MFMA(V,P-reg) under s-perm sigma.
__global__ __launch_bounds__(512, 2) void k_flash(
    const unsigned* __restrict__ qpk, const unsigned* __restrict__ qipk,
    const unsigned* __restrict__ kpk, const unsigned* __restrict__ kipk,
    const unsigned* __restrict__ vpk, unsigned* __restrict__ attpk)
{
    __shared__ __align__(16) _Float16 Kbuf[2][4][4][2][64][8];  // 64KB
    __shared__ __align__(16) _Float16 Vbuf[2][2][4][2][64][8];  // 32KB

    const int tid = threadIdx.x;
    const int w = tid >> 6, lane = tid & 63;
    const int quad = lane >> 4, l15 = lane & 15;
    const int p = blockIdx.x;
    const int bh = (p & 7) * 4 + (p >> 6);
    const int tb = (p >> 3) & 7;
    const size_t bc = (size_t)bh * 64;
    const int tw0 = tb * 256 + w * 16;   // rg adds +128

    half8 aqh[2][4], aql[2][4];
#pragma unroll
    for (int rg = 0; rg < 2; ++rg) {
#pragma unroll
        for (int kc = 0; kc < 4; ++kc) {
#pragma unroll
            for (int j = 0; j < 8; ++j) {
                int d = kc * 32 + quad * 8 + j;
                int t = tw0 + rg * 128 + l15;
                unsigned u = (d < 64) ? qpk[(bc + d) * 2048 + t]
                                      : qipk[(bc + d - 64) * 2048 + t];
                aqh[rg][kc][j] = lo16(u);
                aql[rg][kc][j] = hi16(u);
            }
        }
    }

    f32x4 O1[2][4], O2[2][4];
    const f32x4 zero4 = {0.f, 0.f, 0.f, 0.f};
#pragma unroll
    for (int rg = 0; rg < 2; ++rg)
#pragma unroll
        for (int nt = 0; nt < 4; ++nt) { O1[rg][nt] = zero4; O2[rg][nt] = zero4; }
    float m_[2] = {-3e38f, -3e38f};
    float l_[2] = {0.f, 0.f};

    const int sK = tid & 63;
    const int dc0 = tid >> 6;
    const int stK = sK >> 4;
    const int kcK0 = dc0 >> 2;
    const int laneK = (sK & 15) + ((dc0 & 3) << 4);
    const unsigned* kre = &kpk[(bc + dc0 * 8) * 2048 + sK];
    const unsigned* kim = &kipk[(bc + dc0 * 8) * 2048 + sK];
    const int sc2V = tid >> 8;
    const int ntV = (tid >> 6) & 3, laneV = tid & 63;
    const int dV = ntV * 16 + (laneV & 15);
    const int s0V = sc2V * 32 + (laneV >> 4) * 4;
    const unsigned* vbase = &vpk[(bc + dV) * 2048 + s0V];

    unsigned ka0, ka1, ka2, ka3, ka4, ka5, ka6, ka7;
    unsigned kb0, kb1, kb2, kb3, kb4, kb5, kb6, kb7;
    uint4 va0, va1;
    ka0 = kre[0 * 2048]; ka1 = kre[1 * 2048];
    ka2 = kre[2 * 2048]; ka3 = kre[3 * 2048];
    ka4 = kre[4 * 2048]; ka5 = kre[5 * 2048];
    ka6 = kre[6 * 2048]; ka7 = kre[7 * 2048];
    kb0 = kim[0 * 2048]; kb1 = kim[1 * 2048];
    kb2 = kim[2 * 2048]; kb3 = kim[3 * 2048];
    kb4 = kim[4 * 2048]; kb5 = kim[5 * 2048];
    kb6 = kim[6 * 2048]; kb7 = kim[7 * 2048];
    va0 = *(const uint4*)vbase;
    va1 = *(const uint4*)(vbase + 16);
    write_split(&Kbuf[0][stK][kcK0][0][laneK][0], &Kbuf[0][stK][kcK0][1][laneK][0],
                make_uint4(ka0, ka1, ka2, ka3), make_uint4(ka4, ka5, ka6, ka7));
    write_split(&Kbuf[0][stK][kcK0 + 2][0][laneK][0], &Kbuf[0][stK][kcK0 + 2][1][laneK][0],
                make_uint4(kb0, kb1, kb2, kb3), make_uint4(kb4, kb5, kb6, kb7));
    write_split(&Vbuf[0][sc2V][ntV][0][laneV][0], &Vbuf[0][sc2V][ntV][1][laneV][0],
                va0, va1);
    kre += 64; kim += 64; vbase += 64;
    ka0 = kre[0 * 2048]; ka1 = kre[1 * 2048];
    ka2 = kre[2 * 2048]; ka3 = kre[3 * 2048];
    ka4 = kre[4 * 2048]; ka5 = kre[5 * 2048];
    ka6 = kre[6 * 2048]; ka7 = kre[7 * 2048];
    kb0 = kim[0 * 2048]; kb1 = kim[1 * 2048];
    kb2 = kim[2 * 2048]; kb3 = kim[3 * 2048];
    kb4 = kim[4 * 2048]; kb5 = kim[5 * 2048];
    kb6 = kim[6 * 2048]; kb7 = kim[7 * 2048];
    va0 = *(const uint4*)vbase;
    va1 = *(const uint4*)(vbase + 16);
    __syncthreads();

    for (int it = 0; it < 32; ++it) {
        const int cur = it & 1, nxt = cur ^ 1;
        if (it < 31) {
            write_split(&Kbuf[nxt][stK][kcK0][0][laneK][0],
                        &Kbuf[nxt][stK][kcK0][1][laneK][0],
                        make_uint4(ka0, ka1, ka2, ka3), make_uint4(ka4, ka5, ka6, ka7));
            write_split(&Kbuf[nxt][stK][kcK0 + 2][0][laneK][0],
                        &Kbuf[nxt][stK][kcK0 + 2][1][laneK][0],
                        make_uint4(kb0, kb1, kb2, kb3), make_uint4(kb4, kb5, kb6, kb7));
            write_split(&Vbuf[nxt][sc2V][ntV][0][laneV][0],
                        &Vbuf[nxt][sc2V][ntV][1][laneV][0], va0, va1);
        }
        if (it < 30) {
            kre += 64; kim += 64; vbase += 64;
            ka0 = kre[0 * 2048]; ka1 = kre[1 * 2048];
            ka2 = kre[2 * 2048]; ka3 = kre[3 * 2048];
            ka4 = kre[4 * 2048]; ka5 = kre[5 * 2048];
            ka6 = kre[6 * 2048]; ka7 = kre[7 * 2048];
            kb0 = kim[0 * 2048]; kb1 = kim[1 * 2048];
            kb2 = kim[2 * 2048]; kb3 = kim[3 * 2048];
            kb4 = kim[4 * 2048]; kb5 = kim[5 * 2048];
            kb6 = kim[6 * 2048]; kb7 = kim[7 * 2048];
            va0 = *(const uint4*)vbase;
            va1 = *(const uint4*)(vbase + 16);
        }

        // --- S^T = K.Q^T: 96 MFMA, K read once
        f32x4 S1[2][4], S2[2][4];
#pragma unroll
        for (int rg = 0; rg < 2; ++rg)
#pragma unroll
            for (int st = 0; st < 4; ++st) { S1[rg][st] = zero4; S2[rg][st] = zero4; }
        __builtin_amdgcn_s_setprio(1);
#pragma unroll
        for (int st = 0; st < 4; ++st) {
#pragma unroll
            for (int kc = 0; kc < 4; ++kc) {
                half8 khf = *(half8*)&Kbuf[cur][st][kc][0][lane][0];
                half8 klf = *(half8*)&Kbuf[cur][st][kc][1][lane][0];
#pragma unroll
                for (int rg = 0; rg < 2; ++rg) {
                    S1[rg][st] = MFMA16(khf, aqh[rg][kc], S1[rg][st], 0, 0, 0);
                    S2[rg][st] = MFMA16(klf, aqh[rg][kc], S2[rg][st], 0, 0, 0);
                    S2[rg][st] = MFMA16(khf, aql[rg][kc], S2[rg][st], 0, 0, 0);
                }
            }
        }
        __builtin_amdgcn_s_setprio(0);

        // --- per-lane online softmax with defer-max (THR=8)
        half8 pb[2][2];
#pragma unroll
        for (int rg = 0; rg < 2; ++rg) {
#pragma unroll
            for (int st = 0; st < 4; ++st)
                S1[rg][st] = S1[rg][st] + S2[rg][st] * (1.f / 2048.f);
            float mt = -3e38f;
#pragma unroll
            for (int st = 0; st < 4; ++st)
#pragma unroll
                for (int r = 0; r < 4; ++r)
                    mt = fmaxf(mt, S1[rg][st][r]);
            mt = fmaxf(mt, __shfl_xor(mt, 16));
            mt = fmaxf(mt, __shfl_xor(mt, 32));
            if (!__all(mt <= m_[rg] + 8.f)) {
                float mn2 = fmaxf(m_[rg], mt);
                float al = __expf(m_[rg] - mn2);
                m_[rg] = mn2;
                l_[rg] *= al;
#pragma unroll
                for (int nt = 0; nt < 4; ++nt) { O1[rg][nt] *= al; O2[rg][nt] *= al; }
            }
            float mn = m_[rg];
            float rs = 0.f;
            _Float16 ph[4][4];
#pragma unroll
            for (int st = 0; st < 4; ++st)
#pragma unroll
                for (int r = 0; r < 4; ++r) {
                    float pe = __expf(S1[rg][st][r] - mn);
                    rs += pe;
                    ph[st][r] = (_Float16)pe;
                }
            rs += __shfl_xor(rs, 16);
            rs += __shfl_xor(rs, 32);
            l_[rg] += rs;
#pragma unroll
            for (int sc2 = 0; sc2 < 2; ++sc2) {
                half8 t8;
                t8[0] = ph[2 * sc2][0];     t8[1] = ph[2 * sc2][1];
                t8[2] = ph[2 * sc2][2];     t8[3] = ph[2 * sc2][3];
                t8[4] = ph[2 * sc2 + 1][0]; t8[5] = ph[2 * sc2 + 1][1];
                t8[6] = ph[2 * sc2 + 1][2]; t8[7] = ph[2 * sc2 + 1][3];
                pb[rg][sc2] = t8;
            }
        }

        // --- PV as O^T = MFMA(Vfrag, P): 32 MFMA
        __builtin_amdgcn_s_setprio(1);
#pragma unroll
        for (int sc2 = 0; sc2 < 2; ++sc2) {
#pragma unroll
            for (int nt = 0; nt < 4; ++nt) {
                half8 vh = *(half8*)&Vbuf[cur][sc2][nt][0][lane][0];
                half8 vl = *(half8*)&Vbuf[cur][sc2][nt][1][lane][0];
                O1[0][nt] = MFMA16(vh, pb[0][sc2], O1[0][nt], 0, 0, 0);
                O2[0][nt] = MFMA16(vl, pb[0][sc2], O2[0][nt], 0, 0, 0);
                O1[1][nt] = MFMA16(vh, pb[1][sc2], O1[1][nt], 0, 0, 0);
                O2[1][nt] = MFMA16(vl, pb[1][sc2], O2[1][nt], 0, 0, 0);
            }
        }
        __builtin_amdgcn_s_setprio(0);

        __syncthreads();
    }

    const int b = bh >> 4, h = bh & 15;
#pragma unroll
    for (int rg = 0; rg < 2; ++rg) {
        float inv = 1.0f / l_[rg];
        int t = tw0 + rg * 128 + l15;
        size_t row = (size_t)b * 2048 + t;
#pragma unroll
        for (int nt = 0; nt < 4; ++nt) {
#pragma unroll
            for (int r = 0; r < 4; ++r) {
                float val = (O1[rg][nt][r] + O2[rg][nt][r] * (1.f / 2048.f)) * inv;
                attpk[row * 1024 + h * 64 + nt * 16 + quad * 4 + r] = pack_split(val);
            }
        }
    }
}

// --------------------------------------------------- out GEMM (MFMA f16-split)
__global__ __launch_bounds__(256) void k_gemm_out(
    const unsigned* __restrict__ attpk, const unsigned* __restrict__ wopk,
    const float* __restrict__ bo, float* __restrict__ out)
{
    __shared__ __align__(16) _Float16 Ab[8][2][64][8];
    __shared__ __align__(16) _Float16 Bb[8][2][64][8];
    const int tid = threadIdx.x;
    const int m0 = blockIdx.x * 128, n0 = blockIdx.y * 128;
    const int w = tid >> 6, lane = tid & 63, quad = lane >> 4, l15 = lane & 15;
    const int wm = (w & 1) * 4, wn = (w >> 1) * 4;

    const int chA = tid & 3, rA = tid >> 2;
    const int flA = (rA & 15) + 16 * chA, mtA = rA >> 4;
    const unsigned* gA0 = &attpk[(size_t)(m0 + rA) * 1024 + chA * 8];
    const unsigned* gA1 = gA0 + (size_t)64 * 1024;
    const unsigned* gB0 = &wopk[(size_t)(n0 + rA) * 1024 + chA * 8];
    const unsigned* gB1 = gB0 + (size_t)64 * 1024;

    uint4 pa0 = *(const uint4*)gA0, pa1 = *(const uint4*)(gA0 + 4);
    uint4 pa2 = *(const uint4*)gA1, pa3 = *(const uint4*)(gA1 + 4);
    uint4 pb0 = *(const uint4*)gB0, pb1 = *(const uint4*)(gB0 + 4);
    uint4 pb2 = *(const uint4*)gB1, pb3 = *(const uint4*)(gB1 + 4);

    f32x4 acc1[4][4], acc2[4][4];
    const f32x4 z4 = {0.f, 0.f, 0.f, 0.f};
#pragma unroll
    for (int i = 0; i < 4; ++i)
#pragma unroll
        for (int j = 0; j < 4; ++j) { acc1[i][j] = z4; acc2[i][j] = z4; }

    for (int k0 = 0; k0 < 1024; k0 += 32) {
        __syncthreads();
        write_split(&Ab[mtA][0][flA][0],     &Ab[mtA][1][flA][0],     pa0, pa1);
        write_split(&Ab[mtA + 4][0][flA][0], &Ab[mtA + 4][1][flA][0], pa2, pa3);
        write_split(&Bb[mtA][0][flA][0],     &Bb[mtA][1][flA][0],     pb0, pb1);
        write_split(&Bb[mtA + 4][0][flA][0], &Bb[mtA + 4][1][flA][0], pb2, pb3);
        __syncthreads();
        if (k0 < 992) {
            int kn = k0 + 32;
            pa0 = *(const uint4*)(gA0 + kn); pa1 = *(const uint4*)(gA0 + kn + 4);
            pa2 = *(const uint4*)(gA1 + kn); pa3 = *(const uint4*)(gA1 + kn + 4);
            pb0 = *(const uint4*)(gB0 + kn); pb1 = *(const uint4*)(gB0 + kn + 4);
            pb2 = *(const uint4*)(gB1 + kn); pb3 = *(const uint4*)(gB1 + kn + 4);
        }
        half8 ah[4], al[4];
#pragma unroll
        for (int mt = 0; mt < 4; ++mt) {
            ah[mt] = *(half8*)&Ab[wm + mt][0][lane][0];
            al[mt] = *(half8*)&Ab[wm + mt][1][lane][0];
        }
#pragma unroll
        for (int nt = 0; nt < 4; ++nt) {
            half8 bh = *(half8*)&Bb[wn + nt][0][lane][0];
            half8 bl = *(half8*)&Bb[wn + nt][1][lane][0];
#pragma unroll
            for (int mt = 0; mt < 4; ++mt) {
                acc1[mt][nt] = MFMA16(ah[mt], bh, acc1[mt][nt], 0, 0, 0);
                acc2[mt][nt] = MFMA16(ah[mt], bl, acc2[mt][nt], 0, 0, 0);
                acc2[mt][nt] = MFMA16(al[mt], bh, acc2[mt][nt], 0, 0, 0);
            }
        }
    }
#pragma unroll
    for (int mt = 0; mt < 4; ++mt) {
#pragma unroll
        for (int r_ = 0; r_ < 4; ++r_) {
            int m = m0 + (wm + mt) * 16 + quad * 4 + r_;
            float* orow = &out[(size_t)m * 1024 + n0];
#pragma unroll
            for (int nt = 0; nt < 4; ++nt) {
                int n = (wn + nt) * 16 + l15;
                float val = acc1[mt][nt][r_] + acc2[mt][nt][r_] * (1.f / 2048.f)
                          + bo[n0 + n];
                orow[n] = val;
            }
        }
    }
}

// ------------------------------------------------------------- energy renorm
__global__ __launch_bounds__(256) void k_norm(
    const float* __restrict__ x, float* __restrict__ out,
    const float* __restrict__ en)
{
    const int row = blockIdx.x;
    const int tid = threadIdx.x;
    const float* xr = x + (size_t)row * 1024;
    float* orow = out + (size_t)row * 1024;
    float4 xv = *(const float4*)&xr[tid * 4];
    float4 ov = *(const float4*)&orow[tid * 4];
    float ssx = xv.x * xv.x + xv.y * xv.y + xv.z * xv.z + xv.w * xv.w;
    float sso = ov.x * ov.x + ov.y * ov.y + ov.z * ov.z + ov.w * ov.w;
#pragma unroll
    for (int m = 1; m <= 32; m <<= 1) {
        ssx += __shfl_xor(ssx, m, 64);
        sso += __shfl_xor(sso, m, 64);
    }
    __shared__ float rx[4], ro[4];
    const int wid = tid >> 6;
    if ((tid & 63) == 0) { rx[wid] = ssx; ro[wid] = sso; }
    __syncthreads();
    float tsx = rx[0] + rx[1] + rx[2] + rx[3];
    float tso = ro[0] + ro[1] + ro[2] + ro[3];
    float scale = sqrtf(tsx) / (sqrtf(tso) + 1e-8f) * en[0];
    ov.x *= scale; ov.y *= scale; ov.z *= scale; ov.w *= scale;
    *(float4*)&orow[tid * 4] = ov;
}

// ------------------------------------------------------------- launch
extern "C" void kernel_launch(void* const* d_in, const int* in_sizes, int n_in,
                              void* d_out, int out_size, void* d_ws, size_t ws_size,
                              hipStream_t stream)
{
    const float* x     = (const float*)d_in[0];
    const float* fd    = (const float*)d_in[1];
    const float* wq    = (const float*)d_in[2];
    const float* bq    = (const float*)d_in[3];
    const float* wk    = (const float*)d_in[4];
    const float* bk    = (const float*)d_in[5];
    const float* wv    = (const float*)d_in[6];
    const float* bv    = (const float*)d_in[7];
    const float* wo    = (const float*)d_in[8];
    const float* bo    = (const float*)d_in[9];
    const float* alpha = (const float*)d_in[10];
    const float* fas   = (const float*)d_in[11];
    const float* en    = (const float*)d_in[12];
    float* out = (float*)d_out;
    float* ws  = (float*)d_ws;

    float* qT  = ws;                               // -> qpk -> wopk
    float* kT  = ws + (size_t)1 * 4194304;         // -> kpk
    float* vT  = ws + (size_t)2 * 4194304;         // -> vpk
    float* qiT = ws + (size_t)3 * 4194304;         // w-planes -> qipk
    float* kiT = ws + (size_t)4 * 4194304;         // -> kipk
    float* att = ws + (size_t)5 * 4194304;         // x-planes -> attpk
    float2* tw   = (float2*)(ws + (size_t)6 * 4194304);
    float2* filt = (float2*)(ws + (size_t)6 * 4194304 + 2048);

    _Float16* wpl = (_Float16*)qiT;      // 3 x (2MB hi + 2MB lo) = 12MB
    _Float16* xpl = (_Float16*)att;      // 8MB hi + 8MB lo = 16MB
    unsigned* attpk  = (unsigned*)att;
    unsigned* wopk   = (unsigned*)qT;

    k_init_tables<<<8, 256, 0, stream>>>(tw, filt, fd, alpha, fas);
    k_prep_wpl3<<<dim3(16, 16, 3), 256, 0, stream>>>(wq, wk, wv, wpl);
    k_prep_xpl<<<dim3(64, 16), 256, 0, stream>>>(x, xpl);
    k_gemm_qkv<<<dim3(8, 32, 3), 256, 0, stream>>>(xpl, wpl, bq, bk, bv,
                                                   qT, kT, vT);
    k_fft_filter<<<3072, 256, 0, stream>>>(qT, kT, vT, qiT, kiT, tw, filt);
    k_flash<<<256, 512, 0, stream>>>((const unsigned*)qT, (const unsigned*)qiT,
                                     (const unsigned*)kT, (const unsigned*)kiT,
                                     (const unsigned*)vT, attpk);
    k_prep_w<<<dim3(16, 16), 256, 0, stream>>>(wo, wopk);
    k_gemm_out<<<dim3(32, 8), 256, 0, stream>>>(attpk, wopk, bo, out);
    k_norm<<<4096, 256, 0, stream>>>(x, out, en);
}

// Round 10
// 424.530 us; speedup vs baseline: 1.0690x; 1.0690x over previous
//
#include <hip/hip_runtime.h>
#include <math.h>

// SpectralAttention gfx950 — round 14: fix R13's unpipelined gemm_qkv.
// R13 post-mortem: converting staging to global_load_lds REGRESSED (439->454)
// because the loop became {barrier -> issue loads -> drain barrier -> compute}
// — load latency fully exposed each K-step (R12 had reg-prefetch overlap).
// Fix: double-buffer Ab/Bb (64KB, 2 blk/CU) + m97 schedule: issue next tile's
// 8 global_load_lds BEFORE computing current tile; single barrier/iter drains
// loads that had the whole MFMA phase to land.  Planar preps (validated by
// R13's passing refcheck), flash (148us, Mfma 40, conflicts 0), FFT, gemm_out,
// norm: unchanged.
// B=2, T=2048, C=1024, H=16, HD=64.
//
// Packed split format (u32): lo16 = fp16(v) ["hi" part], hi16 = fp16((v-hi)*2048).
// v = hi + lo/2048 to ~2^-22 rel.  3-term MFMA: D = Ah*Bh + (Ah*Bl + Al*Bh)/2048.
//
// ws layout (floats) with region reuse:
//   [0,  4M)  qT -> qpk -> wopk     [4M, 8M)  kT -> kpk    [8M, 12M) vT -> vpk
//   [12M,16M) w-planes(12MB) -> qipk   [16M,20M) kipk
//   [20M,24M) x-planes(16MB) -> attpk  24M: tables
// total 96 MB + 16 KB

typedef _Float16 half8 __attribute__((ext_vector_type(8)));
typedef float f32x4 __attribute__((ext_vector_type(4)));
#define MFMA16 __builtin_amdgcn_mfma_f32_16x16x32_f16

#define GLOAD16(g, l) __builtin_amdgcn_global_load_lds( \
    (const __attribute__((address_space(1))) void*)(g), \
    (__attribute__((address_space(3))) void*)(l), 16, 0, 0)

__device__ inline unsigned pack_split(float v) {
    _Float16 h = (_Float16)v;
    float r = (v - (float)h) * 2048.0f;
    _Float16 l = (_Float16)r;
    union { _Float16 f; unsigned short u; } a, b;
    a.f = h; b.f = l;
    return (unsigned)a.u | ((unsigned)b.u << 16);
}
__device__ inline void split2(float v, _Float16& h, _Float16& l) {
    h = (_Float16)v;
    l = (_Float16)((v - (float)h) * 2048.0f);
}
__device__ inline _Float16 lo16(unsigned u) {
    union { unsigned short s; _Float16 f; } x; x.s = (unsigned short)(u & 0xffffu); return x.f;
}
__device__ inline _Float16 hi16(unsigned u) {
    union { unsigned short s; _Float16 f; } x; x.s = (unsigned short)(u >> 16); return x.f;
}

// split 8 packed u32 into hi-half8 / lo-half8 via byte-perms, store as 2 b128
__device__ inline void write_split(_Float16* dh, _Float16* dl, uint4 u0, uint4 u1) {
    uint4 lo, hi;
    lo.x = __builtin_amdgcn_perm(u0.y, u0.x, 0x05040100u);
    lo.y = __builtin_amdgcn_perm(u0.w, u0.z, 0x05040100u);
    lo.z = __builtin_amdgcn_perm(u1.y, u1.x, 0x05040100u);
    lo.w = __builtin_amdgcn_perm(u1.w, u1.z, 0x05040100u);
    hi.x = __builtin_amdgcn_perm(u0.y, u0.x, 0x07060302u);
    hi.y = __builtin_amdgcn_perm(u0.w, u0.z, 0x07060302u);
    hi.z = __builtin_amdgcn_perm(u1.y, u1.x, 0x07060302u);
    hi.w = __builtin_amdgcn_perm(u1.w, u1.z, 0x07060302u);
    *(uint4*)dh = lo;
    *(uint4*)dl = hi;
}

// ---------------------------------------------------------------- init tables
__global__ __launch_bounds__(256) void k_init_tables(
    float2* __restrict__ tw, float2* __restrict__ filt,
    const float* __restrict__ fd, const float* __restrict__ alpha,
    const float* __restrict__ fas)
{
    int i = blockIdx.x * 256 + threadIdx.x;
    double aa = (double)alpha[0] + (double)fas[0] * ((double)fd[0] - 1.5);
    if (i < 1024) {
        double ang = -2.0 * 3.14159265358979323846 * (double)i / 2048.0;
        double s, c;
        sincos(ang, &s, &c);
        tw[i] = make_float2((float)c, (float)s);
    }
    if (i < 2048) {
        double fr = (i < 1024) ? (double)i / 2048.0 : ((double)i - 2048.0) / 2048.0;
        double ph = aa * atan(log(fabs(fr) + 1e-10));
        double s, c;
        sincos(ph, &s, &c);
        filt[i] = make_float2((float)c, (float)s);
    }
}

// ---------------------- prep: W^T -> planar hi/lo planes, MFMA-tiled (x3)
// Plane layout (halves): [c/16][k/32][lane=64][j=8], lane = (c&15)+16*((k>>3)&3),
// j = k&7.  Per mat: hi plane 1M halves, lo plane 1M halves (4MB total).
__global__ __launch_bounds__(256) void k_prep_wpl3(
    const float* __restrict__ wq, const float* __restrict__ wk,
    const float* __restrict__ wv, _Float16* __restrict__ wpl)
{
    __shared__ float tile[64][65];
    const int z = blockIdx.z;
    const float* W = (z == 0) ? wq : (z == 1) ? wk : wv;
    _Float16* Whi = wpl + (size_t)z * 2097152;
    _Float16* Wlo = Whi + 1048576;
    const int kb = blockIdx.x * 64, cb = blockIdx.y * 64;
    const int t = threadIdx.x, r = t >> 4, c4 = (t & 15) * 4;
#pragma unroll
    for (int i = 0; i < 4; ++i) {
        int row = r + 16 * i;
        float4 v = *(const float4*)&W[(size_t)(kb + row) * 1024 + cb + c4];
        tile[row][c4 + 0] = v.x; tile[row][c4 + 1] = v.y;
        tile[row][c4 + 2] = v.z; tile[row][c4 + 3] = v.w;
    }
    __syncthreads();
#pragma unroll
    for (int h = 0; h < 2; ++h) {
        int idx = t + h * 256;
        int lane = idx & 63, kt2 = (idx >> 6) & 1, ct = idx >> 7;
        int cl = ct * 16 + (lane & 15);
        int kl = kt2 * 32 + ((lane >> 4) * 8);
        half8 hv, lv;
#pragma unroll
        for (int j = 0; j < 8; ++j) {
            _Float16 hh, ll;
            split2(tile[kl + j][cl], hh, ll);
            hv[j] = hh; lv[j] = ll;
        }
        size_t u = ((size_t)((cb >> 4) + ct) * 32 + (kb >> 5) + kt2) * 64 + lane;
        *(half8*)&Whi[u * 8] = hv;
        *(half8*)&Wlo[u * 8] = lv;
    }
}

// ---------------------- prep: x -> planar hi/lo planes, MFMA-tiled
// Plane (halves): [n/16][c/32][lane=64][j=8], lane=(n&15)+16*((c>>3)&3), j=c&7.
// xhi 4M halves, xlo 4M halves (16MB total).
__global__ __launch_bounds__(256) void k_prep_xpl(
    const float* __restrict__ x, _Float16* __restrict__ xpl)
{
    __shared__ float tile[64][65];
    _Float16* Xhi = xpl;
    _Float16* Xlo = xpl + 4194304;
    const int nb = blockIdx.x * 64, cb = blockIdx.y * 64;
    const int t = threadIdx.x, r = t >> 4, c4 = (t & 15) * 4;
#pragma unroll
    for (int i = 0; i < 4; ++i) {
        int row = r + 16 * i;
        float4 v = *(const float4*)&x[(size_t)(nb + row) * 1024 + cb + c4];
        tile[row][c4 + 0] = v.x; tile[row][c4 + 1] = v.y;
        tile[row][c4 + 2] = v.z; tile[row][c4 + 3] = v.w;
    }
    __syncthreads();
#pragma unroll
    for (int h = 0; h < 2; ++h) {
        int idx = t + h * 256;
        int lane = idx & 63, ct2 = (idx >> 6) & 1, ntl = (idx >> 7) & 3;
        int nl = ntl * 16 + (lane & 15);
        int cl = ct2 * 32 + ((lane >> 4) * 8);
        half8 hv, lv;
#pragma unroll
        for (int j = 0; j < 8; ++j) {
            _Float16 hh, ll;
            split2(tile[nl][cl + j], hh, ll);
            hv[j] = hh; lv[j] = ll;
        }
        size_t u = ((size_t)((nb >> 4) + ntl) * 32 + (cb >> 5) + ct2) * 64 + lane;
        *(half8*)&Xhi[u * 8] = hv;
        *(half8*)&Xlo[u * 8] = lv;
    }
}

// ------------------------------------------------------- prep: W^T (packed, wo)
__global__ __launch_bounds__(256) void k_prep_w(
    const float* __restrict__ W, unsigned* __restrict__ Wpk)
{
    __shared__ float tile[64][65];
    const int kb = blockIdx.x * 64, cb = blockIdx.y * 64;
    const int t = threadIdx.x, r = t >> 4, c4 = (t & 15) * 4;
#pragma unroll
    for (int i = 0; i < 4; ++i) {
        int row = r + 16 * i;
        float4 v = *(const float4*)&W[(size_t)(kb + row) * 1024 + cb + c4];
        tile[row][c4 + 0] = v.x; tile[row][c4 + 1] = v.y;
        tile[row][c4 + 2] = v.z; tile[row][c4 + 3] = v.w;
    }
    __syncthreads();
#pragma unroll
    for (int i = 0; i < 4; ++i) {
        int crow = r + 16 * i;
        uint4 o;
        o.x = pack_split(tile[c4 + 0][crow]);
        o.y = pack_split(tile[c4 + 1][crow]);
        o.z = pack_split(tile[c4 + 2][crow]);
        o.w = pack_split(tile[c4 + 3][crow]);
        *(uint4*)&Wpk[(size_t)(cb + crow) * 1024 + kb + c4] = o;
    }
}

// --------------------------------------------------- QKV GEMM (MFMA f16-split)
// R14: double-buffered LDS + early-issue global_load_lds (m97 schedule).
// Issue tile kt+1's 8 gloads BEFORE computing tile kt; ONE barrier per iter
// (its vmcnt drain lands after the full MFMA phase -> latency hidden).
__global__ __launch_bounds__(256) void k_gemm_qkv(
    const _Float16* __restrict__ xpl, const _Float16* __restrict__ wpl,
    const float* __restrict__ bq, const float* __restrict__ bk,
    const float* __restrict__ bv,
    float* __restrict__ qT, float* __restrict__ kT, float* __restrict__ vT)
{
    __shared__ __align__(16) _Float16 Ab[2][8][2][64][8];   // 32 KB
    __shared__ __align__(16) _Float16 Bb[2][8][2][64][8];   // 32 KB
    const int tid = threadIdx.x;
    const int mat = blockIdx.z;
    const _Float16* Ahi = wpl + (size_t)mat * 2097152;
    const _Float16* Alo = Ahi + 1048576;
    const _Float16* Bhi = xpl;
    const _Float16* Blo = xpl + 4194304;
    const float* bias = (mat == 0) ? bq : (mat == 1) ? bk : bv;
    float* outp       = (mat == 0) ? qT : (mat == 1) ? kT : vT;
    const int m0 = blockIdx.x * 128, n0 = blockIdx.y * 128;
    const int w = tid >> 6, lane = tid & 63, quad = lane >> 4, l15 = lane & 15;
    const int wm = (w & 1) * 4, wn = (w >> 1) * 4;

    // wave w stages segments mt/nt = 2w, 2w+1 (4 waves cover 0..7)
    const int s0 = 2 * w, s1 = 2 * w + 1;
    const size_t aT0 = (size_t)((m0 >> 4) + s0) * 32;   // tile-row base (16B rows)
    const size_t aT1 = aT0 + 32;
    const size_t bT0 = (size_t)((n0 >> 4) + s0) * 32;
    const size_t bT1 = bT0 + 32;
    const int ln8 = lane * 8;

    f32x4 acc1[4][4], acc2[4][4];
    const f32x4 z4 = {0.f, 0.f, 0.f, 0.f};
#pragma unroll
    for (int i = 0; i < 4; ++i)
#pragma unroll
        for (int j = 0; j < 4; ++j) { acc1[i][j] = z4; acc2[i][j] = z4; }

    // prologue: stage tile 0 into buf 0, drain
    {
        size_t oA0 = aT0 * 512 + ln8;
        size_t oA1 = aT1 * 512 + ln8;
        size_t oB0 = bT0 * 512 + ln8;
        size_t oB1 = bT1 * 512 + ln8;
        GLOAD16(Ahi + oA0, &Ab[0][s0][0][0][0]);
        GLOAD16(Alo + oA0, &Ab[0][s0][1][0][0]);
        GLOAD16(Ahi + oA1, &Ab[0][s1][0][0][0]);
        GLOAD16(Alo + oA1, &Ab[0][s1][1][0][0]);
        GLOAD16(Bhi + oB0, &Bb[0][s0][0][0][0]);
        GLOAD16(Blo + oB0, &Bb[0][s0][1][0][0]);
        GLOAD16(Bhi + oB1, &Bb[0][s1][0][0][0]);
        GLOAD16(Blo + oB1, &Bb[0][s1][1][0][0]);
    }
    __syncthreads();

    for (int kt = 0; kt < 32; ++kt) {
        const int cur = kt & 1, nxt = cur ^ 1;
        // ---- issue next tile's loads (in flight during compute)
        if (kt < 31) {
            int kn = kt + 1;
            size_t oA0 = (aT0 + kn) * 512 + ln8;
            size_t oA1 = (aT1 + kn) * 512 + ln8;
            size_t oB0 = (bT0 + kn) * 512 + ln8;
            size_t oB1 = (bT1 + kn) * 512 + ln8;
            GLOAD16(Ahi + oA0, &Ab[nxt][s0][0][0][0]);
            GLOAD16(Alo + oA0, &Ab[nxt][s0][1][0][0]);
            GLOAD16(Ahi + oA1, &Ab[nxt][s1][0][0][0]);
            GLOAD16(Alo + oA1, &Ab[nxt][s1][1][0][0]);
            GLOAD16(Bhi + oB0, &Bb[nxt][s0][0][0][0]);
            GLOAD16(Blo + oB0, &Bb[nxt][s0][1][0][0]);
            GLOAD16(Bhi + oB1, &Bb[nxt][s1][0][0][0]);
            GLOAD16(Blo + oB1, &Bb[nxt][s1][1][0][0]);
        }
        // ---- compute from buf[cur]
        half8 ah[4], al[4];
#pragma unroll
        for (int mt = 0; mt < 4; ++mt) {
            ah[mt] = *(half8*)&Ab[cur][wm + mt][0][lane][0];
            al[mt] = *(half8*)&Ab[cur][wm + mt][1][lane][0];
        }
#pragma unroll
        for (int nt = 0; nt < 4; ++nt) {
            half8 bh = *(half8*)&Bb[cur][wn + nt][0][lane][0];
            half8 bl = *(half8*)&Bb[cur][wn + nt][1][lane][0];
#pragma unroll
            for (int mt = 0; mt < 4; ++mt) {
                acc1[mt][nt] = MFMA16(ah[mt], bh, acc1[mt][nt], 0, 0, 0);
                acc2[mt][nt] = MFMA16(ah[mt], bl, acc2[mt][nt], 0, 0, 0);
                acc2[mt][nt] = MFMA16(al[mt], bh, acc2[mt][nt], 0, 0, 0);
            }
        }
        __syncthreads();   // drains vmcnt: next-tile loads landed during MFMA
    }
    const int b_ = n0 >> 11, t0 = n0 & 2047;
#pragma unroll
    for (int mt = 0; mt < 4; ++mt) {
#pragma unroll
        for (int r_ = 0; r_ < 4; ++r_) {
            int m = m0 + (wm + mt) * 16 + quad * 4 + r_;
            float bs = bias[m];
            float* orow = &outp[(size_t)(b_ * 1024 + m) * 2048 + t0];
#pragma unroll
            for (int nt = 0; nt < 4; ++nt) {
                float val = acc1[mt][nt][r_] + acc2[mt][nt][r_] * (1.f / 2048.f) + bs;
                orow[(wn + nt) * 16 + l15] = val;
            }
        }
    }
}

// ------------------------------------------------------------- FFT + filter
// Real-FFT pairing: rows (2p, 2p+1) real -> one complex FFT, Hermitian split.
__global__ __launch_bounds__(256) void k_fft_filter(
    float* __restrict__ qT, float* __restrict__ kT, float* __restrict__ vT,
    float* __restrict__ qiT, float* __restrict__ kiT,
    const float2* __restrict__ tw, const float2* __restrict__ filt)
{
    __shared__ float2 sf[2048];
    const int bid = blockIdx.x;          // 0..3071
    const int mat = bid >> 10;
    const int pair = bid & 1023;
    const int seq0 = pair * 2, seq1 = seq0 + 1;
    float* base = (mat == 0) ? qT : (mat == 1) ? kT : vT;
    float* src0 = base + (size_t)seq0 * 2048;
    float* src1 = base + (size_t)seq1 * 2048;
    const int tid = threadIdx.x;

    for (int i = tid; i < 2048; i += 256) {
        int j = (int)(__brev((unsigned)i) >> 21);
        sf[j] = make_float2(src0[i], src1[i]);
    }
    __syncthreads();
    for (int st = 1; st <= 11; ++st) {
        const int half = 1 << (st - 1);
        const int shift = 11 - st;
        for (int u = tid; u < 1024; u += 256) {
            int pos = u & (half - 1);
            int bi = 2 * u - pos;
            float2 w = tw[pos << shift];
            float2 a = sf[bi], b = sf[bi + half];
            float tr = w.x * b.x - w.y * b.y;
            float ti = w.x * b.y + w.y * b.x;
            sf[bi]        = make_float2(a.x + tr, a.y + ti);
            sf[bi + half] = make_float2(a.x - tr, a.y - ti);
        }
        __syncthreads();
    }
    unsigned* dr0 = (unsigned*)src0;
    unsigned* dr1 = (unsigned*)src1;
    unsigned* di0 = (mat == 0) ? (unsigned*)(qiT + (size_t)seq0 * 2048)
                               : (unsigned*)(kiT + (size_t)seq0 * 2048);
    unsigned* di1 = (mat == 0) ? (unsigned*)(qiT + (size_t)seq1 * 2048)
                               : (unsigned*)(kiT + (size_t)seq1 * 2048);
    for (int i = tid; i < 2048; i += 256) {
        float2 z  = sf[i];
        float2 zm = sf[(2048 - i) & 2047];
        float Are = 0.5f * (z.x + zm.x), Aim = 0.5f * (z.y - zm.y);
        float Bre = 0.5f * (z.y + zm.y), Bim = 0.5f * (zm.x - z.x);
        float2 f = filt[i];
        float re0 = Are * f.x - Aim * f.y, im0 = Are * f.y + Aim * f.x;
        float re1 = Bre * f.x - Bim * f.y, im1 = Bre * f.y + Bim * f.x;
        if (mat == 0) {
            dr0[i] = pack_split(0.125f * re0); di0[i] = pack_split(0.125f * im0);
            dr1[i] = pack_split(0.125f * re1); di1[i] = pack_split(0.125f * im1);
        } else if (mat == 1) {
            dr0[i] = pack_split(re0); di0[i] = pack_split(-im0);
            dr1[i] = pack_split(re1); di1[i] = pack_split(-im1);
        } else {
            dr0[i] = pack_split(re0);
            dr1[i] = pack_split(re1);
        }
    }
}

// ------------------------------------------------------------- flash (MFMA f16)
// Unchanged: 256 blocks x 512 thr (8 waves); wave owns 32 rows (2 row-groups);
// s-step 64; dbuf K/V, ONE barrier/iter; S^T=MFMA(K,Q); per-lane softmax +
// defer-max(THR=8); O^T=MFMA(V,P-reg) under s-perm sigma.
__global__ __launch_bounds__(512, 2) void k_flash(
    const unsigned* __restrict__ qpk, const unsigned* __restrict__ qipk,
    const unsigned* __restrict__ kpk, const unsigned* __restrict__ kipk,
    const unsigned* __restrict__ vpk, unsigned* __restrict__ attpk)
{
    __shared__ __align__(16) _Float16 Kbuf[2][4][4][2][64][8];  // 64KB
    __shared__ __align__(16) _Float16 Vbuf[2][2][4][2][64][8];  // 32KB

    const int tid = threadIdx.x;
    const int w = tid >> 6, lane = tid & 63;
    const int quad = lane >> 4, l15 = lane & 15;
    const int p = blockIdx.x;
    const int bh = (p & 7) * 4 + (p >> 6);
    const int tb = (p >> 3) & 7;
    const size_t bc = (size_t)bh * 64;
    const int tw0 = tb * 256 + w * 16;   // rg adds +128

    half8 aqh[2][4], aql[2][4];
#pragma unroll
    for (int rg = 0; rg < 2; ++rg) {
#pragma unroll
        for (int kc = 0; kc < 4; ++kc) {
#pragma unroll
            for (int j = 0; j < 8; ++j) {
                int d = kc * 32 + quad * 8 + j;
                int t = tw0 + rg * 128 + l15;
                unsigned u = (d < 64) ? qpk[(bc + d) * 2048 + t]
                                      : qipk[(bc + d - 64) * 2048 + t];
                aqh[rg][kc][j] = lo16(u);
                aql[rg][kc][j] = hi16(u);
            }
        }
    }

    f32x4 O1[2][4], O2[2][4];
    const f32x4 zero4 = {0.f, 0.f, 0.f, 0.f};
#pragma unroll
    for (int rg = 0; rg < 2; ++rg)
#pragma unroll
        for (int nt = 0; nt < 4; ++nt) { O1[rg][nt] = zero4; O2[rg][nt] = zero4; }
    float m_[2] = {-3e38f, -3e38f};
    float l_[2] = {0.f, 0.f};

    const int sK = tid & 63;
    const int dc0 = tid >> 6;
    const int stK = sK >> 4;
    const int kcK0 = dc0 >> 2;
    const int laneK = (sK & 15) + ((dc0 & 3) << 4);
    const unsigned* kre = &kpk[(bc + dc0 * 8) * 2048 + sK];
    const unsigned* kim = &kipk[(bc + dc0 * 8) * 2048 + sK];
    const int sc2V = tid >> 8;
    const int ntV = (tid >> 6) & 3, laneV = tid & 63;
    const int dV = ntV * 16 + (laneV & 15);
    const int s0V = sc2V * 32 + (laneV >> 4) * 4;
    const unsigned* vbase = &vpk[(bc + dV) * 2048 + s0V];

    unsigned ka0, ka1, ka2, ka3, ka4, ka5, ka6, ka7;
    unsigned kb0, kb1, kb2, kb3, kb4, kb5, kb6, kb7;
    uint4 va0, va1;
    ka0 = kre[0 * 2048]; ka1 = kre[1 * 2048];
    ka2 = kre[2 * 2048]; ka3 = kre[3 * 2048];
    ka4 = kre[4 * 2048]; ka5 = kre[5 * 2048];
    ka6 = kre[6 * 2048]; ka7 = kre[7 * 2048];
    kb0 = kim[0 * 2048]; kb1 = kim[1 * 2048];
    kb2 = kim[2 * 2048]; kb3 = kim[3 * 2048];
    kb4 = kim[4 * 2048]; kb5 = kim[5 * 2048];
    kb6 = kim[6 * 2048]; kb7 = kim[7 * 2048];
    va0 = *(const uint4*)vbase;
    va1 = *(const uint4*)(vbase + 16);
    write_split(&Kbuf[0][stK][kcK0][0][laneK][0], &Kbuf[0][stK][kcK0][1][laneK][0],
                make_uint4(ka0, ka1, ka2, ka3), make_uint4(ka4, ka5, ka6, ka7));
    write_split(&Kbuf[0][stK][kcK0 + 2][0][laneK][0], &Kbuf[0][stK][kcK0 + 2][1][laneK][0],
                make_uint4(kb0, kb1, kb2, kb3), make_uint4(kb4, kb5, kb6, kb7));
    write_split(&Vbuf[0][sc2V][ntV][0][laneV][0], &Vbuf[0][sc2V][ntV][1][laneV][0],
                va0, va1);
    kre += 64; kim += 64; vbase += 64;
    ka0 = kre[0 * 2048]; ka1 = kre[1 * 2048];
    ka2 = kre[2 * 2048]; ka3 = kre[3 * 2048];
    ka4 = kre[4 * 2048]; ka5 = kre[5 * 2048];
    ka6 = kre[6 * 2048]; ka7 = kre[7 * 2048];
    kb0 = kim[0 * 2048]; kb1 = kim[1 * 2048];
    kb2 = kim[2 * 2048]; kb3 = kim[3 * 2048];
    kb4 = kim[4 * 2048]; kb5 = kim[5 * 2048];
    kb6 = kim[6 * 2048]; kb7 = kim[7 * 2048];
    va0 = *(const uint4*)vbase;
    va1 = *(const uint4*)(vbase + 16);
    __syncthreads();

    for (int it = 0; it < 32; ++it) {
        const int cur = it & 1, nxt = cur ^ 1;
        if (it < 31) {
            write_split(&Kbuf[nxt][stK][kcK0][0][laneK][0],
                        &Kbuf[nxt][stK][kcK0][1][laneK][0],
                        make_uint4(ka0, ka1, ka2, ka3), make_uint4(ka4, ka5, ka6, ka7));
            write_split(&Kbuf[nxt][stK][kcK0 + 2][0][laneK][0],
                        &Kbuf[nxt][stK][kcK0 + 2][1][laneK][0],
                        make_uint4(kb0, kb1, kb2, kb3), make_uint4(kb4, kb5, kb6, kb7));
            write_split(&Vbuf[nxt][sc2V][ntV][0][laneV][0],
                        &Vbuf[nxt][sc2V][ntV][1][laneV][0], va0, va1);
        }
        if (it < 30) {
            kre += 64; kim += 64; vbase += 64;
            ka0 = kre[0 * 2048]; ka1 = kre[1 * 2048];
            ka2 = kre[2 * 2048]; ka3 = kre[3 * 2048];
            ka4 = kre[4 * 2048]; ka5 = kre[5 * 2048];
            ka6 = kre[6 * 2048]; ka7 = kre[7 * 2048];
            kb0 = kim[0 * 2048]; kb1 = kim[1 * 2048];
            kb2 = kim[2 * 2048]; kb3 = kim[3 * 2048];
            kb4 = kim[4 * 2048]; kb5 = kim[5 * 2048];
            kb6 = kim[6 * 2048]; kb7 = kim[7 * 2048];
            va0 = *(const uint4*)vbase;
            va1 = *(const uint4*)(vbase + 16);
        }

        // --- S^T = K.Q^T: 96 MFMA, K read once
        f32x4 S1[2][4], S2[2][4];
#pragma unroll
        for (int rg = 0; rg < 2; ++rg)
#pragma unroll
            for (int st = 0; st < 4; ++st) { S1[rg][st] = zero4; S2[rg][st] = zero4; }
        __builtin_amdgcn_s_setprio(1);
#pragma unroll
        for (int st = 0; st < 4; ++st) {
#pragma unroll
            for (int kc = 0; kc < 4; ++kc) {
                half8 khf = *(half8*)&Kbuf[cur][st][kc][0][lane][0];
                half8 klf = *(half8*)&Kbuf[cur][st][kc][1][lane][0];
#pragma unroll
                for (int rg = 0; rg < 2; ++rg) {
                    S1[rg][st] = MFMA16(khf, aqh[rg][kc], S1[rg][st], 0, 0, 0);
                    S2[rg][st] = MFMA16(klf, aqh[rg][kc], S2[rg][st], 0, 0, 0);
                    S2[rg][st] = MFMA16(khf, aql[rg][kc], S2[rg][st], 0, 0, 0);
                }
            }
        }
        __builtin_amdgcn_s_setprio(0);

        // --- per-lane online softmax with defer-max (THR=8)
        half8 pb[2][2];
#pragma unroll
        for (int rg = 0; rg < 2; ++rg) {
#pragma unroll
            for (int st = 0; st < 4; ++st)
                S1[rg][st] = S1[rg][st] + S2[rg][st] * (1.f / 2048.f);
            float mt = -3e38f;
#pragma unroll
            for (int st = 0; st < 4; ++st)
#pragma unroll
                for (int r = 0; r < 4; ++r)
                    mt = fmaxf(mt, S1[rg][st][r]);
            mt = fmaxf(mt, __shfl_xor(mt, 16));
            mt = fmaxf(mt, __shfl_xor(mt, 32));
            if (!__all(mt <= m_[rg] + 8.f)) {
                float mn2 = fmaxf(m_[rg], mt);
                float al = __expf(m_[rg] - mn2);
                m_[rg] = mn2;
                l_[rg] *= al;
#pragma unroll
                for (int nt = 0; nt < 4; ++nt) { O1[rg][nt] *= al; O2[rg][nt] *= al; }
            }
            float mn = m_[rg];
            float rs = 0.f;
            _Float16 ph[4][4];
#pragma unroll
            for (int st = 0; st < 4; ++st)
#pragma unroll
                for (int r = 0; r < 4; ++r) {
                    float pe = __expf(S1[rg][st][r] - mn);
                    rs += pe;
                    ph[st][r] = (_Float16)pe;
                }
            rs += __shfl_xor(rs, 16);
            rs += __shfl_xor(rs, 32);
            l_[rg] += rs;
#pragma unroll
            for (int sc2 = 0; sc2 < 2; ++sc2) {
                half8 t8;
                t8[0] = ph[2 * sc2][0];     t8[1] = ph[2 * sc2][1];
                t8[2] = ph[2 * sc2][2];     t8[3] = ph[2 * sc2][3];
                t8[4] = ph[2 * sc2 + 1][0]; t8[5] = ph[2 * sc2 + 1][1];
                t8[6] = ph[2 * sc2 + 1][2]; t8[7] = ph[2 * sc2 + 1][3];
                pb[rg][sc2] = t8;
            }
        }

        // --- PV as O^T = MFMA(Vfrag, P): 32 MFMA
        __builtin_amdgcn_s_setprio(1);
#pragma unroll
        for (int sc2 = 0; sc2 < 2; ++sc2) {
#pragma unroll
            for (int nt = 0; nt < 4; ++nt) {
                half8 vh = *(half8*)&Vbuf[cur][sc2][nt][0][lane][0];
                half8 vl = *(half8*)&Vbuf[cur][sc2][nt][1][lane][0];
                O1[0][nt] = MFMA16(vh, pb[0][sc2], O1[0][nt], 0, 0, 0);
                O2[0][nt] = MFMA16(vl, pb[0][sc2], O2[0][nt], 0, 0, 0);
                O1[1][nt] = MFMA16(vh, pb[1][sc2], O1[1][nt], 0, 0, 0);
                O2[1][nt] = MFMA16(vl, pb[1][sc2], O2[1][nt], 0, 0, 0);
            }
        }
        __builtin_amdgcn_s_setprio(0);

        __syncthreads();
    }

    const int b = bh >> 4, h = bh & 15;
#pragma unroll
    for (int rg = 0; rg < 2; ++rg) {
        float inv = 1.0f / l_[rg];
        int t = tw0 + rg * 128 + l15;
        size_t row = (size_t)b * 2048 + t;
#pragma unroll
        for (int nt = 0; nt < 4; ++nt) {
#pragma unroll
            for (int r = 0; r < 4; ++r) {
                float val = (O1[rg][nt][r] + O2[rg][nt][r] * (1.f / 2048.f)) * inv;
                attpk[row * 1024 + h * 64 + nt * 16 + quad * 4 + r] = pack_split(val);
            }
        }
    }
}

// --------------------------------------------------- out GEMM (MFMA f16-split)
__global__ __launch_bounds__(256) void k_gemm_out(
    const unsigned* __restrict__ attpk, const unsigned* __restrict__ wopk,
    const float* __restrict__ bo, float* __restrict__ out)
{
    __shared__ __align__(16) _Float16 Ab[8][2][64][8];
    __shared__ __align__(16) _Float16 Bb[8][2][64][8];
    const int tid = threadIdx.x;
    const int m0 = blockIdx.x * 128, n0 = blockIdx.y * 128;
    const int w = tid >> 6, lane = tid & 63, quad = lane >> 4, l15 = lane & 15;
    const int wm = (w & 1) * 4, wn = (w >> 1) * 4;

    const int chA = tid & 3, rA = tid >> 2;
    const int flA = (rA & 15) + 16 * chA, mtA = rA >> 4;
    const unsigned* gA0 = &attpk[(size_t)(m0 + rA) * 1024 + chA * 8];
    const unsigned* gA1 = gA0 + (size_t)64 * 1024;
    const unsigned* gB0 = &wopk[(size_t)(n0 + rA) * 1024 + chA * 8];
    const unsigned* gB1 = gB0 + (size_t)64 * 1024;

    uint4 pa0 = *(const uint4*)gA0, pa1 = *(const uint4*)(gA0 + 4);
    uint4 pa2 = *(const uint4*)gA1, pa3 = *(const uint4*)(gA1 + 4);
    uint4 pb0 = *(const uint4*)gB0, pb1 = *(const uint4*)(gB0 + 4);
    uint4 pb2 = *(const uint4*)gB1, pb3 = *(const uint4*)(gB1 + 4);

    f32x4 acc1[4][4], acc2[4][4];
    const f32x4 z4 = {0.f, 0.f, 0.f, 0.f};
#pragma unroll
    for (int i = 0; i < 4; ++i)
#pragma unroll
        for (int j = 0; j < 4; ++j) { acc1[i][j] = z4; acc2[i][j] = z4; }

    for (int k0 = 0; k0 < 1024; k0 += 32) {
        __syncthreads();
        write_split(&Ab[mtA][0][flA][0],     &Ab[mtA][1][flA][0],     pa0, pa1);
        write_split(&Ab[mtA + 4][0][flA][0], &Ab[mtA + 4][1][flA][0], pa2, pa3);
        write_split(&Bb[mtA][0][flA][0],     &Bb[mtA][1][flA][0],     pb0, pb1);
        write_split(&Bb[mtA + 4][0][flA][0], &Bb[mtA + 4][1][flA][0], pb2, pb3);
        __syncthreads();
        if (k0 < 992) {
            int kn = k0 + 32;
            pa0 = *(const uint4*)(gA0 + kn); pa1 = *(const uint4*)(gA0 + kn + 4);
            pa2 = *(const uint4*)(gA1 + kn); pa3 = *(const uint4*)(gA1 + kn + 4);
            pb0 = *(const uint4*)(gB0 + kn); pb1 = *(const uint4*)(gB0 + kn + 4);
            pb2 = *(const uint4*)(gB1 + kn); pb3 = *(const uint4*)(gB1 + kn + 4);
        }
        half8 ah[4], al[4];
#pragma unroll
        for (int mt = 0; mt < 4; ++mt) {
            ah[mt] = *(half8*)&Ab[wm + mt][0][lane][0];
            al[mt] = *(half8*)&Ab[wm + mt][1][lane][0];
        }
#pragma unroll
        for (int nt = 0; nt < 4; ++nt) {
            half8 bh = *(half8*)&Bb[wn + nt][0][lane][0];
            half8 bl = *(half8*)&Bb[wn + nt][1][lane][0];
#pragma unroll
            for (int mt = 0; mt < 4; ++mt) {
                acc1[mt][nt] = MFMA16(ah[mt], bh, acc1[mt][nt], 0, 0, 0);
                acc2[mt][nt] = MFMA16(ah[mt], bl, acc2[mt][nt], 0, 0, 0);
                acc2[mt][nt] = MFMA16(al[mt], bh, acc2[mt][nt], 0, 0, 0);
            }
        }
    }
#pragma unroll
    for (int mt = 0; mt < 4; ++mt) {
#pragma unroll
        for (int r_ = 0; r_ < 4; ++r_) {
            int m = m0 + (wm + mt) * 16 + quad * 4 + r_;
            float* orow = &out[(size_t)m * 1024 + n0];
#pragma unroll
            for (int nt = 0; nt < 4; ++nt) {
                int n = (wn + nt) * 16 + l15;
                float val = acc1[mt][nt][r_] + acc2[mt][nt][r_] * (1.f / 2048.f)
                          + bo[n0 + n];
                orow[n] = val;
            }
        }
    }
}

// ------------------------------------------------------------- energy renorm
__global__ __launch_bounds__(256) void k_norm(
    const float* __restrict__ x, float* __restrict__ out,
    const float* __restrict__ en)
{
    const int row = blockIdx.x;
    const int tid = threadIdx.x;
    const float* xr = x + (size_t)row * 1024;
    float* orow = out + (size_t)row * 1024;
    float4 xv = *(const float4*)&xr[tid * 4];
    float4 ov = *(const float4*)&orow[tid * 4];
    float ssx = xv.x * xv.x + xv.y * xv.y + xv.z * xv.z + xv.w * xv.w;
    float sso = ov.x * ov.x + ov.y * ov.y + ov.z * ov.z + ov.w * ov.w;
#pragma unroll
    for (int m = 1; m <= 32; m <<= 1) {
        ssx += __shfl_xor(ssx, m, 64);
        sso += __shfl_xor(sso, m, 64);
    }
    __shared__ float rx[4], ro[4];
    const int wid = tid >> 6;
    if ((tid & 63) == 0) { rx[wid] = ssx; ro[wid] = sso; }
    __syncthreads();
    float tsx = rx[0] + rx[1] + rx[2] + rx[3];
    float tso = ro[0] + ro[1] + ro[2] + ro[3];
    float scale = sqrtf(tsx) / (sqrtf(tso) + 1e-8f) * en[0];
    ov.x *= scale; ov.y *= scale; ov.z *= scale; ov.w *= scale;
    *(float4*)&orow[tid * 4] = ov;
}

// ------------------------------------------------------------- launch
extern "C" void kernel_launch(void* const* d_in, const int* in_sizes, int n_in,
                              void* d_out, int out_size, void* d_ws, size_t ws_size,
                              hipStream_t stream)
{
    const float* x     = (const float*)d_in[0];
    const float* fd    = (const float*)d_in[1];
    const float* wq    = (const float*)d_in[2];
    const float* bq    = (const float*)d_in[3];
    const float* wk    = (const float*)d_in[4];
    const float* bk    = (const float*)d_in[5];
    const float* wv    = (const float*)d_in[6];
    const float* bv    = (const float*)d_in[7];
    const float* wo    = (const float*)d_in[8];
    const float* bo    = (const float*)d_in[9];
    const float* alpha = (const float*)d_in[10];
    const float* fas   = (const float*)d_in[11];
    const float* en    = (const float*)d_in[12];
    float* out = (float*)d_out;
    float* ws  = (float*)d_ws;

    float* qT  = ws;                               // -> qpk -> wopk
    float* kT  = ws + (size_t)1 * 4194304;         // -> kpk
    float* vT  = ws + (size_t)2 * 4194304;         // -> vpk
    float* qiT = ws + (size_t)3 * 4194304;         // w-planes -> qipk
    float* kiT = ws + (size_t)4 * 4194304;         // -> kipk
    float* att = ws + (size_t)5 * 4194304;         // x-planes -> attpk
    float2* tw   = (float2*)(ws + (size_t)6 * 4194304);
    float2* filt = (float2*)(ws + (size_t)6 * 4194304 + 2048);

    _Float16* wpl = (_Float16*)qiT;      // 3 x (2MB hi + 2MB lo) = 12MB
    _Float16* xpl = (_Float16*)att;      // 8MB hi + 8MB lo = 16MB
    unsigned* attpk  = (unsigned*)att;
    unsigned* wopk   = (unsigned*)qT;

    k_init_tables<<<8, 256, 0, stream>>>(tw, filt, fd, alpha, fas);
    k_prep_wpl3<<<dim3(16, 16, 3), 256, 0, stream>>>(wq, wk, wv, wpl);
    k_prep_xpl<<<dim3(64, 16), 256, 0, stream>>>(x, xpl);
    k_gemm_qkv<<<dim3(8, 32, 3), 256, 0, stream>>>(xpl, wpl, bq, bk, bv,
                                                   qT, kT, vT);
    k_fft_filter<<<3072, 256, 0, stream>>>(qT, kT, vT, qiT, kiT, tw, filt);
    k_flash<<<256, 512, 0, stream>>>((const unsigned*)qT, (const unsigned*)qiT,
                                     (const unsigned*)kT, (const unsigned*)kiT,
                                     (const unsigned*)vT, attpk);
    k_prep_w<<<dim3(16, 16), 256, 0, stream>>>(wo, wopk);
    k_gemm_out<<<dim3(32, 8), 256, 0, stream>>>(attpk, wopk, bo, out);
    k_norm<<<4096, 256, 0, stream>>>(x, out, en);
}

// Round 11
// 423.441 us; speedup vs baseline: 1.0718x; 1.0026x over previous
//
#include <hip/hip_runtime.h>
#include <math.h>

// SpectralAttention gfx950 — round 15: radix-4 FFT + gemm_out on the R14
// planar pipeline.
//  (1) k_fft_filter: fuse radix-2 stage pairs into radix-4 passes.
//      With tw[k]=e^{-2pi ik/2048}: W=tw[m<<s], W2=tw[m<<(s-1)], W3=-i*W2
//      (h*2^(s-1)=512, tw[512]=-i).  12 barriers -> 6, LDS traffic halved.
//  (2) k_flash epilogue writes attended directly as planar hi/lo MFMA-tiled
//      planes; k_gemm_out becomes a clone of R14's pipelined gemm_qkv
//      (dbuf LDS + early-issue global_load_lds, 1 barrier/iter); wo gets a
//      single-matrix planar prep.  LDS fragment contents bit-identical to
//      the verified R12 layout.
// R14 verified: total 424.5us; flash 149.7 (Mfma 40.8 / conflicts 0);
// gemm_qkv on m97 schedule.  gemm_qkv/flash-core/preps/norm unchanged.
// B=2, T=2048, C=1024, H=16, HD=64.
//
// Packed split format: hi = fp16(v), lo = fp16((v-hi)*2048);
// v = hi + lo/2048 to ~2^-22 rel.  3-term MFMA: D = Ah*Bh + (Ah*Bl + Al*Bh)/2048.
//
// ws layout (floats) with region reuse:
//   [0,  4M)  qT -> qpk -> wopl     [4M, 8M)  kT -> kpk    [8M, 12M) vT -> vpk
//   [12M,16M) w-planes(12MB) -> qipk   [16M,20M) kipk
//   [20M,24M) x-planes(16MB) -> att-planes(16MB)  24M: tables
// total 96 MB + 16 KB

typedef _Float16 half8 __attribute__((ext_vector_type(8)));
typedef _Float16 half4 __attribute__((ext_vector_type(4)));
typedef float f32x4 __attribute__((ext_vector_type(4)));
#define MFMA16 __builtin_amdgcn_mfma_f32_16x16x32_f16

#define GLOAD16(g, l) __builtin_amdgcn_global_load_lds( \
    (const __attribute__((address_space(1))) void*)(g), \
    (__attribute__((address_space(3))) void*)(l), 16, 0, 0)

__device__ inline void split2(float v, _Float16& h, _Float16& l) {
    h = (_Float16)v;
    l = (_Float16)((v - (float)h) * 2048.0f);
}
__device__ inline unsigned pack_split(float v) {
    _Float16 h, l;
    split2(v, h, l);
    union { _Float16 f; unsigned short u; } a, b;
    a.f = h; b.f = l;
    return (unsigned)a.u | ((unsigned)b.u << 16);
}
__device__ inline _Float16 lo16(unsigned u) {
    union { unsigned short s; _Float16 f; } x; x.s = (unsigned short)(u & 0xffffu); return x.f;
}
__device__ inline _Float16 hi16(unsigned u) {
    union { unsigned short s; _Float16 f; } x; x.s = (unsigned short)(u >> 16); return x.f;
}
__device__ inline float2 cmul(float2 a, float2 b) {
    return make_float2(a.x * b.x - a.y * b.y, a.x * b.y + a.y * b.x);
}

// split 8 packed u32 into hi-half8 / lo-half8 via byte-perms, store as 2 b128
__device__ inline void write_split(_Float16* dh, _Float16* dl, uint4 u0, uint4 u1) {
    uint4 lo, hi;
    lo.x = __builtin_amdgcn_perm(u0.y, u0.x, 0x05040100u);
    lo.y = __builtin_amdgcn_perm(u0.w, u0.z, 0x05040100u);
    lo.z = __builtin_amdgcn_perm(u1.y, u1.x, 0x05040100u);
    lo.w = __builtin_amdgcn_perm(u1.w, u1.z, 0x05040100u);
    hi.x = __builtin_amdgcn_perm(u0.y, u0.x, 0x07060302u);
    hi.y = __builtin_amdgcn_perm(u0.w, u0.z, 0x07060302u);
    hi.z = __builtin_amdgcn_perm(u1.y, u1.x, 0x07060302u);
    hi.w = __builtin_amdgcn_perm(u1.w, u1.z, 0x07060302u);
    *(uint4*)dh = lo;
    *(uint4*)dl = hi;
}

// ---------------------------------------------------------------- init tables
__global__ __launch_bounds__(256) void k_init_tables(
    float2* __restrict__ tw, float2* __restrict__ filt,
    const float* __restrict__ fd, const float* __restrict__ alpha,
    const float* __restrict__ fas)
{
    int i = blockIdx.x * 256 + threadIdx.x;
    double aa = (double)alpha[0] + (double)fas[0] * ((double)fd[0] - 1.5);
    if (i < 1024) {
        double ang = -2.0 * 3.14159265358979323846 * (double)i / 2048.0;
        double s, c;
        sincos(ang, &s, &c);
        tw[i] = make_float2((float)c, (float)s);
    }
    if (i < 2048) {
        double fr = (i < 1024) ? (double)i / 2048.0 : ((double)i - 2048.0) / 2048.0;
        double ph = aa * atan(log(fabs(fr) + 1e-10));
        double s, c;
        sincos(ph, &s, &c);
        filt[i] = make_float2((float)c, (float)s);
    }
}

// ---------------------- prep: W^T -> planar hi/lo planes, MFMA-tiled (x3)
// Plane (halves): [c/16][k/32][lane=64][j=8], lane=(c&15)+16*((k>>3)&3), j=k&7.
__global__ __launch_bounds__(256) void k_prep_wpl3(
    const float* __restrict__ wq, const float* __restrict__ wk,
    const float* __restrict__ wv, _Float16* __restrict__ wpl)
{
    __shared__ float tile[64][65];
    const int z = blockIdx.z;
    const float* W = (z == 0) ? wq : (z == 1) ? wk : wv;
    _Float16* Whi = wpl + (size_t)z * 2097152;
    _Float16* Wlo = Whi + 1048576;
    const int kb = blockIdx.x * 64, cb = blockIdx.y * 64;
    const int t = threadIdx.x, r = t >> 4, c4 = (t & 15) * 4;
#pragma unroll
    for (int i = 0; i < 4; ++i) {
        int row = r + 16 * i;
        float4 v = *(const float4*)&W[(size_t)(kb + row) * 1024 + cb + c4];
        tile[row][c4 + 0] = v.x; tile[row][c4 + 1] = v.y;
        tile[row][c4 + 2] = v.z; tile[row][c4 + 3] = v.w;
    }
    __syncthreads();
#pragma unroll
    for (int h = 0; h < 2; ++h) {
        int idx = t + h * 256;
        int lane = idx & 63, kt2 = (idx >> 6) & 1, ct = idx >> 7;
        int cl = ct * 16 + (lane & 15);
        int kl = kt2 * 32 + ((lane >> 4) * 8);
        half8 hv, lv;
#pragma unroll
        for (int j = 0; j < 8; ++j) {
            _Float16 hh, ll;
            split2(tile[kl + j][cl], hh, ll);
            hv[j] = hh; lv[j] = ll;
        }
        size_t u = ((size_t)((cb >> 4) + ct) * 32 + (kb >> 5) + kt2) * 64 + lane;
        *(half8*)&Whi[u * 8] = hv;
        *(half8*)&Wlo[u * 8] = lv;
    }
}

// ---------------------- prep: single W^T -> planar planes (wo)
__global__ __launch_bounds__(256) void k_prep_wpl1(
    const float* __restrict__ W, _Float16* __restrict__ wpl)
{
    __shared__ float tile[64][65];
    _Float16* Whi = wpl;
    _Float16* Wlo = wpl + 1048576;
    const int kb = blockIdx.x * 64, cb = blockIdx.y * 64;
    const int t = threadIdx.x, r = t >> 4, c4 = (t & 15) * 4;
#pragma unroll
    for (int i = 0; i < 4; ++i) {
        int row = r + 16 * i;
        float4 v = *(const float4*)&W[(size_t)(kb + row) * 1024 + cb + c4];
        tile[row][c4 + 0] = v.x; tile[row][c4 + 1] = v.y;
        tile[row][c4 + 2] = v.z; tile[row][c4 + 3] = v.w;
    }
    __syncthreads();
#pragma unroll
    for (int h = 0; h < 2; ++h) {
        int idx = t + h * 256;
        int lane = idx & 63, kt2 = (idx >> 6) & 1, ct = idx >> 7;
        int cl = ct * 16 + (lane & 15);
        int kl = kt2 * 32 + ((lane >> 4) * 8);
        half8 hv, lv;
#pragma unroll
        for (int j = 0; j < 8; ++j) {
            _Float16 hh, ll;
            split2(tile[kl + j][cl], hh, ll);
            hv[j] = hh; lv[j] = ll;
        }
        size_t u = ((size_t)((cb >> 4) + ct) * 32 + (kb >> 5) + kt2) * 64 + lane;
        *(half8*)&Whi[u * 8] = hv;
        *(half8*)&Wlo[u * 8] = lv;
    }
}

// ---------------------- prep: x -> planar hi/lo planes, MFMA-tiled
__global__ __launch_bounds__(256) void k_prep_xpl(
    const float* __restrict__ x, _Float16* __restrict__ xpl)
{
    __shared__ float tile[64][65];
    _Float16* Xhi = xpl;
    _Float16* Xlo = xpl + 4194304;
    const int nb = blockIdx.x * 64, cb = blockIdx.y * 64;
    const int t = threadIdx.x, r = t >> 4, c4 = (t & 15) * 4;
#pragma unroll
    for (int i = 0; i < 4; ++i) {
        int row = r + 16 * i;
        float4 v = *(const float4*)&x[(size_t)(nb + row) * 1024 + cb + c4];
        tile[row][c4 + 0] = v.x; tile[row][c4 + 1] = v.y;
        tile[row][c4 + 2] = v.z; tile[row][c4 + 3] = v.w;
    }
    __syncthreads();
#pragma unroll
    for (int h = 0; h < 2; ++h) {
        int idx = t + h * 256;
        int lane = idx & 63, ct2 = (idx >> 6) & 1, ntl = (idx >> 7) & 3;
        int nl = ntl * 16 + (lane & 15);
        int cl = ct2 * 32 + ((lane >> 4) * 8);
        half8 hv, lv;
#pragma unroll
        for (int j = 0; j < 8; ++j) {
            _Float16 hh, ll;
            split2(tile[nl][cl + j], hh, ll);
            hv[j] = hh; lv[j] = ll;
        }
        size_t u = ((size_t)((nb >> 4) + ntl) * 32 + (cb >> 5) + ct2) * 64 + lane;
        *(half8*)&Xhi[u * 8] = hv;
        *(half8*)&Xlo[u * 8] = lv;
    }
}

// --------------------------------------------------- QKV GEMM (MFMA f16-split)
// R14: double-buffered LDS + early-issue global_load_lds, 1 barrier/iter.
__global__ __launch_bounds__(256) void k_gemm_qkv(
    const _Float16* __restrict__ xpl, const _Float16* __restrict__ wpl,
    const float* __restrict__ bq, const float* __restrict__ bk,
    const float* __restrict__ bv,
    float* __restrict__ qT, float* __restrict__ kT, float* __restrict__ vT)
{
    __shared__ __align__(16) _Float16 Ab[2][8][2][64][8];   // 32 KB
    __shared__ __align__(16) _Float16 Bb[2][8][2][64][8];   // 32 KB
    const int tid = threadIdx.x;
    const int mat = blockIdx.z;
    const _Float16* Ahi = wpl + (size_t)mat * 2097152;
    const _Float16* Alo = Ahi + 1048576;
    const _Float16* Bhi = xpl;
    const _Float16* Blo = xpl + 4194304;
    const float* bias = (mat == 0) ? bq : (mat == 1) ? bk : bv;
    float* outp       = (mat == 0) ? qT : (mat == 1) ? kT : vT;
    const int m0 = blockIdx.x * 128, n0 = blockIdx.y * 128;
    const int w = tid >> 6, lane = tid & 63, quad = lane >> 4, l15 = lane & 15;
    const int wm = (w & 1) * 4, wn = (w >> 1) * 4;

    const int s0 = 2 * w, s1 = 2 * w + 1;
    const size_t aT0 = (size_t)((m0 >> 4) + s0) * 32;
    const size_t aT1 = aT0 + 32;
    const size_t bT0 = (size_t)((n0 >> 4) + s0) * 32;
    const size_t bT1 = bT0 + 32;
    const int ln8 = lane * 8;

    f32x4 acc1[4][4], acc2[4][4];
    const f32x4 z4 = {0.f, 0.f, 0.f, 0.f};
#pragma unroll
    for (int i = 0; i < 4; ++i)
#pragma unroll
        for (int j = 0; j < 4; ++j) { acc1[i][j] = z4; acc2[i][j] = z4; }

    {
        size_t oA0 = aT0 * 512 + ln8;
        size_t oA1 = aT1 * 512 + ln8;
        size_t oB0 = bT0 * 512 + ln8;
        size_t oB1 = bT1 * 512 + ln8;
        GLOAD16(Ahi + oA0, &Ab[0][s0][0][0][0]);
        GLOAD16(Alo + oA0, &Ab[0][s0][1][0][0]);
        GLOAD16(Ahi + oA1, &Ab[0][s1][0][0][0]);
        GLOAD16(Alo + oA1, &Ab[0][s1][1][0][0]);
        GLOAD16(Bhi + oB0, &Bb[0][s0][0][0][0]);
        GLOAD16(Blo + oB0, &Bb[0][s0][1][0][0]);
        GLOAD16(Bhi + oB1, &Bb[0][s1][0][0][0]);
        GLOAD16(Blo + oB1, &Bb[0][s1][1][0][0]);
    }
    __syncthreads();

    for (int kt = 0; kt < 32; ++kt) {
        const int cur = kt & 1, nxt = cur ^ 1;
        if (kt < 31) {
            int kn = kt + 1;
            size_t oA0 = (aT0 + kn) * 512 + ln8;
            size_t oA1 = (aT1 + kn) * 512 + ln8;
            size_t oB0 = (bT0 + kn) * 512 + ln8;
            size_t oB1 = (bT1 + kn) * 512 + ln8;
            GLOAD16(Ahi + oA0, &Ab[nxt][s0][0][0][0]);
            GLOAD16(Alo + oA0, &Ab[nxt][s0][1][0][0]);
            GLOAD16(Ahi + oA1, &Ab[nxt][s1][0][0][0]);
            GLOAD16(Alo + oA1, &Ab[nxt][s1][1][0][0]);
            GLOAD16(Bhi + oB0, &Bb[nxt][s0][0][0][0]);
            GLOAD16(Blo + oB0, &Bb[nxt][s0][1][0][0]);
            GLOAD16(Bhi + oB1, &Bb[nxt][s1][0][0][0]);
            GLOAD16(Blo + oB1, &Bb[nxt][s1][1][0][0]);
        }
        half8 ah[4], al[4];
#pragma unroll
        for (int mt = 0; mt < 4; ++mt) {
            ah[mt] = *(half8*)&Ab[cur][wm + mt][0][lane][0];
            al[mt] = *(half8*)&Ab[cur][wm + mt][1][lane][0];
        }
#pragma unroll
        for (int nt = 0; nt < 4; ++nt) {
            half8 bh = *(half8*)&Bb[cur][wn + nt][0][lane][0];
            half8 bl = *(half8*)&Bb[cur][wn + nt][1][lane][0];
#pragma unroll
            for (int mt = 0; mt < 4; ++mt) {
                acc1[mt][nt] = MFMA16(ah[mt], bh, acc1[mt][nt], 0, 0, 0);
                acc2[mt][nt] = MFMA16(ah[mt], bl, acc2[mt][nt], 0, 0, 0);
                acc2[mt][nt] = MFMA16(al[mt], bh, acc2[mt][nt], 0, 0, 0);
            }
        }
        __syncthreads();
    }
    const int b_ = n0 >> 11, t0 = n0 & 2047;
#pragma unroll
    for (int mt = 0; mt < 4; ++mt) {
#pragma unroll
        for (int r_ = 0; r_ < 4; ++r_) {
            int m = m0 + (wm + mt) * 16 + quad * 4 + r_;
            float bs = bias[m];
            float* orow = &outp[(size_t)(b_ * 1024 + m) * 2048 + t0];
#pragma unroll
            for (int nt = 0; nt < 4; ++nt) {
                float val = acc1[mt][nt][r_] + acc2[mt][nt][r_] * (1.f / 2048.f) + bs;
                orow[(wn + nt) * 16 + l15] = val;
            }
        }
    }
}

// ------------------------------------------------------------- FFT + filter
// Real-FFT pairing + R15 radix-4 butterflies (5 passes + final radix-2).
__global__ __launch_bounds__(256) void k_fft_filter(
    float* __restrict__ qT, float* __restrict__ kT, float* __restrict__ vT,
    float* __restrict__ qiT, float* __restrict__ kiT,
    const float2* __restrict__ tw, const float2* __restrict__ filt)
{
    __shared__ float2 sf[2048];
    const int bid = blockIdx.x;          // 0..3071
    const int mat = bid >> 10;
    const int pair = bid & 1023;
    const int seq0 = pair * 2, seq1 = seq0 + 1;
    float* base = (mat == 0) ? qT : (mat == 1) ? kT : vT;
    float* src0 = base + (size_t)seq0 * 2048;
    float* src1 = base + (size_t)seq1 * 2048;
    const int tid = threadIdx.x;

    for (int i = tid; i < 2048; i += 256) {
        int j = (int)(__brev((unsigned)i) >> 21);
        sf[j] = make_float2(src0[i], src1[i]);
    }
    __syncthreads();
    // radix-4 passes: stages (1,2),(3,4),(5,6),(7,8),(9,10)
#pragma unroll
    for (int st = 1; st <= 9; st += 2) {
        const int h = 1 << (st - 1);
        const int s = 11 - st;
        for (int u = tid; u < 512; u += 256) {
            int m = u & (h - 1);
            int g = u >> (st - 1);
            int bi = g * 4 * h + m;
            float2 a = sf[bi], b = sf[bi + h], c = sf[bi + 2 * h], d = sf[bi + 3 * h];
            float2 W  = tw[m << s];
            float2 W2 = tw[m << (s - 1)];
            float2 wb = cmul(W, b), wd = cmul(W, d);
            float2 a1 = make_float2(a.x + wb.x, a.y + wb.y);
            float2 b1 = make_float2(a.x - wb.x, a.y - wb.y);
            float2 c1 = make_float2(c.x + wd.x, c.y + wd.y);
            float2 d1 = make_float2(c.x - wd.x, c.y - wd.y);
            float2 w2c = cmul(W2, c1);
            float2 w2d = cmul(W2, d1);
            float2 w3d = make_float2(w2d.y, -w2d.x);   // -i * w2d
            sf[bi]         = make_float2(a1.x + w2c.x, a1.y + w2c.y);
            sf[bi + 2 * h] = make_float2(a1.x - w2c.x, a1.y - w2c.y);
            sf[bi + h]     = make_float2(b1.x + w3d.x, b1.y + w3d.y);
            sf[bi + 3 * h] = make_float2(b1.x - w3d.x, b1.y - w3d.y);
        }
        __syncthreads();
    }
    // final radix-2 stage 11: half = 1024
    for (int u = tid; u < 1024; u += 256) {
        float2 w = tw[u];
        float2 a = sf[u], b = sf[u + 1024];
        float2 wb = cmul(w, b);
        sf[u]        = make_float2(a.x + wb.x, a.y + wb.y);
        sf[u + 1024] = make_float2(a.x - wb.x, a.y - wb.y);
    }
    __syncthreads();

    unsigned* dr0 = (unsigned*)src0;
    unsigned* dr1 = (unsigned*)src1;
    unsigned* di0 = (mat == 0) ? (unsigned*)(qiT + (size_t)seq0 * 2048)
                               : (unsigned*)(kiT + (size_t)seq0 * 2048);
    unsigned* di1 = (mat == 0) ? (unsigned*)(qiT + (size_t)seq1 * 2048)
                               : (unsigned*)(kiT + (size_t)seq1 * 2048);
    for (int i = tid; i < 2048; i += 256) {
        float2 z  = sf[i];
        float2 zm = sf[(2048 - i) & 2047];
        float Are = 0.5f * (z.x + zm.x), Aim = 0.5f * (z.y - zm.y);
        float Bre = 0.5f * (z.y + zm.y), Bim = 0.5f * (zm.x - z.x);
        float2 f = filt[i];
        float re0 = Are * f.x - Aim * f.y, im0 = Are * f.y + Aim * f.x;
        float re1 = Bre * f.x - Bim * f.y, im1 = Bre * f.y + Bim * f.x;
        if (mat == 0) {
            dr0[i] = pack_split(0.125f * re0); di0[i] = pack_split(0.125f * im0);
            dr1[i] = pack_split(0.125f * re1); di1[i] = pack_split(0.125f * im1);
        } else if (mat == 1) {
            dr0[i] = pack_split(re0); di0[i] = pack_split(-im0);
            dr1[i] = pack_split(re1); di1[i] = pack_split(-im1);
        } else {
            dr0[i] = pack_split(re0);
            dr1[i] = pack_split(re1);
        }
    }
}

// ------------------------------------------------------------- flash (MFMA f16)
// Core unchanged.  R15: epilogue writes attended directly as planar hi/lo
// planes ([m/16][k/32][lane][8], m = b*2048+t, k = h*64+nt*16+quad*4+r).
__global__ __launch_bounds__(512, 2) void k_flash(
    const unsigned* __restrict__ qpk, const unsigned* __restrict__ qipk,
    const unsigned* __restrict__ kpk, const unsigned* __restrict__ kipk,
    const unsigned* __restrict__ vpk, _Float16* __restrict__ attpl)
{
    __shared__ __align__(16) _Float16 Kbuf[2][4][4][2][64][8];  // 64KB
    __shared__ __align__(16) _Float16 Vbuf[2][2][4][2][64][8];  // 32KB

    const int tid = threadIdx.x;
    const int w = tid >> 6, lane = tid & 63;
    const int quad = lane >> 4, l15 = lane & 15;
    const int p = blockIdx.x;
    const int bh = (p & 7) * 4 + (p >> 6);
    const int tb = (p >> 3) & 7;
    const size_t bc = (size_t)bh * 64;
    const int tw0 = tb * 256 + w * 16;   // rg adds +128

    half8 aqh[2][4], aql[2][4];
#pragma unroll
    for (int rg = 0; rg < 2; ++rg) {
#pragma unroll
        for (int kc = 0; kc < 4; ++kc) {
#pragma unroll
            for (int j = 0; j < 8; ++j) {
                int d = kc * 32 + quad * 8 + j;
                int t = tw0 + rg * 128 + l15;
                unsigned u = (d < 64) ? qpk[(bc + d) * 2048 + t]
                                      : qipk[(bc + d - 64) * 2048 + t];
                aqh[rg][kc][j] = lo16(u);
                aql[rg][kc][j] = hi16(u);
            }
        }
    }

    f32x4 O1[2][4], O2[2][4];
    const f32x4 zero4 = {0.f, 0.f, 0.f, 0.f};
#pragma unroll
    for (int rg = 0; rg < 2; ++rg)
#pragma unroll
        for (int nt = 0; nt < 4; ++nt) { O1[rg][nt] = zero4; O2[rg][nt] = zero4; }
    float m_[2] = {-3e38f, -3e38f};
    float l_[2] = {0.f, 0.f};

    const int sK = tid & 63;
    const int dc0 = tid >> 6;
    const int stK = sK >> 4;
    const int kcK0 = dc0 >> 2;
    const int laneK = (sK & 15) + ((dc0 & 3) << 4);
    const unsigned* kre = &kpk[(bc + dc0 * 8) * 2048 + sK];
    const unsigned* kim = &kipk[(bc + dc0 * 8) * 2048 + sK];
    const int sc2V = tid >> 8;
    const int ntV = (tid >> 6) & 3, laneV = tid & 63;
    const int dV = ntV * 16 + (laneV & 15);
    const int s0V = sc2V * 32 + (laneV >> 4) * 4;
    const unsigned* vbase = &vpk[(bc + dV) * 2048 + s0V];

    unsigned ka0, ka1, ka2, ka3, ka4, ka5, ka6, ka7;
    unsigned kb0, kb1, kb2, kb3, kb4, kb5, kb6, kb7;
    uint4 va0, va1;
    ka0 = kre[0 * 2048]; ka1 = kre[1 * 2048];
    ka2 = kre[2 * 2048]; ka3 = kre[3 * 2048];
    ka4 = kre[4 * 2048]; ka5 = kre[5 * 2048];
    ka6 = kre[6 * 2048]; ka7 = kre[7 * 2048];
    kb0 = kim[0 * 2048]; kb1 = kim[1 * 2048];
    kb2 = kim[2 * 2048]; kb3 = kim[3 * 2048];
    kb4 = kim[4 * 2048]; kb5 = kim[5 * 2048];
    kb6 = kim[6 * 2048]; kb7 = kim[7 * 2048];
    va0 = *(const uint4*)vbase;
    va1 = *(const uint4*)(vbase + 16);
    write_split(&Kbuf[0][stK][kcK0][0][laneK][0], &Kbuf[0][stK][kcK0][1][laneK][0],
                make_uint4(ka0, ka1, ka2, ka3), make_uint4(ka4, ka5, ka6, ka7));
    write_split(&Kbuf[0][stK][kcK0 + 2][0][laneK][0], &Kbuf[0][stK][kcK0 + 2][1][laneK][0],
                make_uint4(kb0, kb1, kb2, kb3), make_uint4(kb4, kb5, kb6, kb7));
    write_split(&Vbuf[0][sc2V][ntV][0][laneV][0], &Vbuf[0][sc2V][ntV][1][laneV][0],
                va0, va1);
    kre += 64; kim += 64; vbase += 64;
    ka0 = kre[0 * 2048]; ka1 = kre[1 * 2048];
    ka2 = kre[2 * 2048]; ka3 = kre[3 * 2048];
    ka4 = kre[4 * 2048]; ka5 = kre[5 * 2048];
    ka6 = kre[6 * 2048]; ka7 = kre[7 * 2048];
    kb0 = kim[0 * 2048]; kb1 = kim[1 * 2048];
    kb2 = kim[2 * 2048]; kb3 = kim[3 * 2048];
    kb4 = kim[4 * 2048]; kb5 = kim[5 * 2048];
    kb6 = kim[6 * 2048]; kb7 = kim[7 * 2048];
    va0 = *(const uint4*)vbase;
    va1 = *(const uint4*)(vbase + 16);
    __syncthreads();

    for (int it = 0; it < 32; ++it) {
        const int cur = it & 1, nxt = cur ^ 1;
        if (it < 31) {
            write_split(&Kbuf[nxt][stK][kcK0][0][laneK][0],
                        &Kbuf[nxt][stK][kcK0][1][laneK][0],
                        make_uint4(ka0, ka1, ka2, ka3), make_uint4(ka4, ka5, ka6, ka7));
            write_split(&Kbuf[nxt][stK][kcK0 + 2][0][laneK][0],
                        &Kbuf[nxt][stK][kcK0 + 2][1][laneK][0],
                        make_uint4(kb0, kb1, kb2, kb3), make_uint4(kb4, kb5, kb6, kb7));
            write_split(&Vbuf[nxt][sc2V][ntV][0][laneV][0],
                        &Vbuf[nxt][sc2V][ntV][1][laneV][0], va0, va1);
        }
        if (it < 30) {
            kre += 64; kim += 64; vbase += 64;
            ka0 = kre[0 * 2048]; ka1 = kre[1 * 2048];
            ka2 = kre[2 * 2048]; ka3 = kre[3 * 2048];
            ka4 = kre[4 * 2048]; ka5 = kre[5 * 2048];
            ka6 = kre[6 * 2048]; ka7 = kre[7 * 2048];
            kb0 = kim[0 * 2048]; kb1 = kim[1 * 2048];
            kb2 = kim[2 * 2048]; kb3 = kim[3 * 2048];
            kb4 = kim[4 * 2048]; kb5 = kim[5 * 2048];
            kb6 = kim[6 * 2048]; kb7 = kim[7 * 2048];
            va0 = *(const uint4*)vbase;
            va1 = *(const uint4*)(vbase + 16);
        }

        // --- S^T = K.Q^T: 96 MFMA, K read once
        f32x4 S1[2][4], S2[2][4];
#pragma unroll
        for (int rg = 0; rg < 2; ++rg)
#pragma unroll
            for (int st = 0; st < 4; ++st) { S1[rg][st] = zero4; S2[rg][st] = zero4; }
        __builtin_amdgcn_s_setprio(1);
#pragma unroll
        for (int st = 0; st < 4; ++st) {
#pragma unroll
            for (int kc = 0; kc < 4; ++kc) {
                half8 khf = *(half8*)&Kbuf[cur][st][kc][0][lane][0];
                half8 klf = *(half8*)&Kbuf[cur][st][kc][1][lane][0];
#pragma unroll
                for (int rg = 0; rg < 2; ++rg) {
                    S1[rg][st] = MFMA16(khf, aqh[rg][kc], S1[rg][st], 0, 0, 0);
                    S2[rg][st] = MFMA16(klf, aqh[rg][kc], S2[rg][st], 0, 0, 0);
                    S2[rg][st] = MFMA16(khf, aql[rg][kc], S2[rg][st], 0, 0, 0);
                }
            }
        }
        __builtin_amdgcn_s_setprio(0);

        // --- per-lane online softmax with defer-max (THR=8)
        half8 pb[2][2];
#pragma unroll
        for (int rg = 0; rg < 2; ++rg) {
#pragma unroll
            for (int st = 0; st < 4; ++st)
                S1[rg][st] = S1[rg][st] + S2[rg][st] * (1.f / 2048.f);
            float mt = -3e38f;
#pragma unroll
            for (int st = 0; st < 4; ++st)
#pragma unroll
                for (int r = 0; r < 4; ++r)
                    mt = fmaxf(mt, S1[rg][st][r]);
            mt = fmaxf(mt, __shfl_xor(mt, 16));
            mt = fmaxf(mt, __shfl_xor(mt, 32));
            if (!__all(mt <= m_[rg] + 8.f)) {
                float mn2 = fmaxf(m_[rg], mt);
                float al = __expf(m_[rg] - mn2);
                m_[rg] = mn2;
                l_[rg] *= al;
#pragma unroll
                for (int nt = 0; nt < 4; ++nt) { O1[rg][nt] *= al; O2[rg][nt] *= al; }
            }
            float mn = m_[rg];
            float rs = 0.f;
            _Float16 ph[4][4];
#pragma unroll
            for (int st = 0; st < 4; ++st)
#pragma unroll
                for (int r = 0; r < 4; ++r) {
                    float pe = __expf(S1[rg][st][r] - mn);
                    rs += pe;
                    ph[st][r] = (_Float16)pe;
                }
            rs += __shfl_xor(rs, 16);
            rs += __shfl_xor(rs, 32);
            l_[rg] += rs;
#pragma unroll
            for (int sc2 = 0; sc2 < 2; ++sc2) {
                half8 t8;
                t8[0] = ph[2 * sc2][0];     t8[1] = ph[2 * sc2][1];
                t8[2] = ph[2 * sc2][2];     t8[3] = ph[2 * sc2][3];
                t8[4] = ph[2 * sc2 + 1][0]; t8[5] = ph[2 * sc2 + 1][1];
                t8[6] = ph[2 * sc2 + 1][2]; t8[7] = ph[2 * sc2 + 1][3];
                pb[rg][sc2] = t8;
            }
        }

        // --- PV as O^T = MFMA(Vfrag, P): 32 MFMA
        __builtin_amdgcn_s_setprio(1);
#pragma unroll
        for (int sc2 = 0; sc2 < 2; ++sc2) {
#pragma unroll
            for (int nt = 0; nt < 4; ++nt) {
                half8 vh = *(half8*)&Vbuf[cur][sc2][nt][0][lane][0];
                half8 vl = *(half8*)&Vbuf[cur][sc2][nt][1][lane][0];
                O1[0][nt] = MFMA16(vh, pb[0][sc2], O1[0][nt], 0, 0, 0);
                O2[0][nt] = MFMA16(vl, pb[0][sc2], O2[0][nt], 0, 0, 0);
                O1[1][nt] = MFMA16(vh, pb[1][sc2], O1[1][nt], 0, 0, 0);
                O2[1][nt] = MFMA16(vl, pb[1][sc2], O2[1][nt], 0, 0, 0);
            }
        }
        __builtin_amdgcn_s_setprio(0);

        __syncthreads();
    }

    // epilogue: write planar planes.  lane holds m = b*2048 + t (t col l15),
    // k = h*64 + nt*16 + quad*4 + r.  (k>>5)=h*2+(nt>>1);
    // lane' = (m&15) + 16*((nt*2+(quad>>1))&3); j = (quad&1)*4 + r.
    const int b = bh >> 4, h = bh & 15;
#pragma unroll
    for (int rg = 0; rg < 2; ++rg) {
        float inv = 1.0f / l_[rg];
        int mrow = b * 2048 + tw0 + rg * 128 + l15;
        size_t mt32 = (size_t)(mrow >> 4) * 32;
#pragma unroll
        for (int nt = 0; nt < 4; ++nt) {
            size_t u = (mt32 + h * 2 + (nt >> 1)) * 512
                     + (size_t)(l15 + 16 * ((nt * 2 + (quad >> 1)) & 3)) * 8
                     + (quad & 1) * 4;
            half4 hv, lv;
#pragma unroll
            for (int r = 0; r < 4; ++r) {
                float val = (O1[rg][nt][r] + O2[rg][nt][r] * (1.f / 2048.f)) * inv;
                _Float16 hh, ll;
                split2(val, hh, ll);
                hv[r] = hh; lv[r] = ll;
            }
            *(half4*)&attpl[u] = hv;
            *(half4*)&attpl[4194304 + u] = lv;
        }
    }
}

// --------------------------------------------------- out GEMM (MFMA f16-split)
// R15: R14 pipeline (planar planes, dbuf LDS, early global_load_lds).
__global__ __launch_bounds__(256) void k_gemm_out(
    const _Float16* __restrict__ attpl, const _Float16* __restrict__ wopl,
    const float* __restrict__ bo, float* __restrict__ out)
{
    __shared__ __align__(16) _Float16 Ab[2][8][2][64][8];   // 32 KB
    __shared__ __align__(16) _Float16 Bb[2][8][2][64][8];   // 32 KB
    const int tid = threadIdx.x;
    const _Float16* Ahi = attpl;
    const _Float16* Alo = attpl + 4194304;
    const _Float16* Bhi = wopl;
    const _Float16* Blo = wopl + 1048576;
    const int m0 = blockIdx.x * 128, n0 = blockIdx.y * 128;
    const int w = tid >> 6, lane = tid & 63, quad = lane >> 4, l15 = lane & 15;
    const int wm = (w & 1) * 4, wn = (w >> 1) * 4;

    const int s0 = 2 * w, s1 = 2 * w + 1;
    const size_t aT0 = (size_t)((m0 >> 4) + s0) * 32;
    const size_t aT1 = aT0 + 32;
    const size_t bT0 = (size_t)((n0 >> 4) + s0) * 32;
    const size_t bT1 = bT0 + 32;
    const int ln8 = lane * 8;

    f32x4 acc1[4][4], acc2[4][4];
    const f32x4 z4 = {0.f, 0.f, 0.f, 0.f};
#pragma unroll
    for (int i = 0; i < 4; ++i)
#pragma unroll
        for (int j = 0; j < 4; ++j) { acc1[i][j] = z4; acc2[i][j] = z4; }

    {
        size_t oA0 = aT0 * 512 + ln8;
        size_t oA1 = aT1 * 512 + ln8;
        size_t oB0 = bT0 * 512 + ln8;
        size_t oB1 = bT1 * 512 + ln8;
        GLOAD16(Ahi + oA0, &Ab[0][s0][0][0][0]);
        GLOAD16(Alo + oA0, &Ab[0][s0][1][0][0]);
        GLOAD16(Ahi + oA1, &Ab[0][s1][0][0][0]);
        GLOAD16(Alo + oA1, &Ab[0][s1][1][0][0]);
        GLOAD16(Bhi + oB0, &Bb[0][s0][0][0][0]);
        GLOAD16(Blo + oB0, &Bb[0][s0][1][0][0]);
        GLOAD16(Bhi + oB1, &Bb[0][s1][0][0][0]);
        GLOAD16(Blo + oB1, &Bb[0][s1][1][0][0]);
    }
    __syncthreads();

    for (int kt = 0; kt < 32; ++kt) {
        const int cur = kt & 1, nxt = cur ^ 1;
        if (kt < 31) {
            int kn = kt + 1;
            size_t oA0 = (aT0 + kn) * 512 + ln8;
            size_t oA1 = (aT1 + kn) * 512 + ln8;
            size_t oB0 = (bT0 + kn) * 512 + ln8;
            size_t oB1 = (bT1 + kn) * 512 + ln8;
            GLOAD16(Ahi + oA0, &Ab[nxt][s0][0][0][0]);
            GLOAD16(Alo + oA0, &Ab[nxt][s0][1][0][0]);
            GLOAD16(Ahi + oA1, &Ab[nxt][s1][0][0][0]);
            GLOAD16(Alo + oA1, &Ab[nxt][s1][1][0][0]);
            GLOAD16(Bhi + oB0, &Bb[nxt][s0][0][0][0]);
            GLOAD16(Blo + oB0, &Bb[nxt][s0][1][0][0]);
            GLOAD16(Bhi + oB1, &Bb[nxt][s1][0][0][0]);
            GLOAD16(Blo + oB1, &Bb[nxt][s1][1][0][0]);
        }
        half8 ah[4], al[4];
#pragma unroll
        for (int mt = 0; mt < 4; ++mt) {
            ah[mt] = *(half8*)&Ab[cur][wm + mt][0][lane][0];
            al[mt] = *(half8*)&Ab[cur][wm + mt][1][lane][0];
        }
#pragma unroll
        for (int nt = 0; nt < 4; ++nt) {
            half8 bh = *(half8*)&Bb[cur][wn + nt][0][lane][0];
            half8 bl = *(half8*)&Bb[cur][wn + nt][1][lane][0];
#pragma unroll
            for (int mt = 0; mt < 4; ++mt) {
                acc1[mt][nt] = MFMA16(ah[mt], bh, acc1[mt][nt], 0, 0, 0);
                acc2[mt][nt] = MFMA16(ah[mt], bl, acc2[mt][nt], 0, 0, 0);
                acc2[mt][nt] = MFMA16(al[mt], bh, acc2[mt][nt], 0, 0, 0);
            }
        }
        __syncthreads();
    }
#pragma unroll
    for (int mt = 0; mt < 4; ++mt) {
#pragma unroll
        for (int r_ = 0; r_ < 4; ++r_) {
            int m = m0 + (wm + mt) * 16 + quad * 4 + r_;
            float* orow = &out[(size_t)m * 1024 + n0];
#pragma unroll
            for (int nt = 0; nt < 4; ++nt) {
                int n = (wn + nt) * 16 + l15;
                float val = acc1[mt][nt][r_] + acc2[mt][nt][r_] * (1.f / 2048.f)
                          + bo[n0 + n];
                orow[n] = val;
            }
        }
    }
}

// ------------------------------------------------------------- energy renorm
__global__ __launch_bounds__(256) void k_norm(
    const float* __restrict__ x, float* __restrict__ out,
    const float* __restrict__ en)
{
    const int row = blockIdx.x;
    const int tid = threadIdx.x;
    const float* xr = x + (size_t)row * 1024;
    float* orow = out + (size_t)row * 1024;
    float4 xv = *(const float4*)&xr[tid * 4];
    float4 ov = *(const float4*)&orow[tid * 4];
    float ssx = xv.x * xv.x + xv.y * xv.y + xv.z * xv.z + xv.w * xv.w;
    float sso = ov.x * ov.x + ov.y * ov.y + ov.z * ov.z + ov.w * ov.w;
#pragma unroll
    for (int m = 1; m <= 32; m <<= 1) {
        ssx += __shfl_xor(ssx, m, 64);
        sso += __shfl_xor(sso, m, 64);
    }
    __shared__ float rx[4], ro[4];
    const int wid = tid >> 6;
    if ((tid & 63) == 0) { rx[wid] = ssx; ro[wid] = sso; }
    __syncthreads();
    float tsx = rx[0] + rx[1] + rx[2] + rx[3];
    float tso = ro[0] + ro[1] + ro[2] + ro[3];
    float scale = sqrtf(tsx) / (sqrtf(tso) + 1e-8f) * en[0];
    ov.x *= scale; ov.y *= scale; ov.z *= scale; ov.w *= scale;
    *(float4*)&orow[tid * 4] = ov;
}

// ------------------------------------------------------------- launch
extern "C" void kernel_launch(void* const* d_in, const int* in_sizes, int n_in,
                              void* d_out, int out_size, void* d_ws, size_t ws_size,
                              hipStream_t stream)
{
    const float* x     = (const float*)d_in[0];
    const float* fd    = (const float*)d_in[1];
    const float* wq    = (const float*)d_in[2];
    const float* bq    = (const float*)d_in[3];
    const float* wk    = (const float*)d_in[4];
    const float* bk    = (const float*)d_in[5];
    const float* wv    = (const float*)d_in[6];
    const float* bv    = (const float*)d_in[7];
    const float* wo    = (const float*)d_in[8];
    const float* bo    = (const float*)d_in[9];
    const float* alpha = (const float*)d_in[10];
    const float* fas   = (const float*)d_in[11];
    const float* en    = (const float*)d_in[12];
    float* out = (float*)d_out;
    float* ws  = (float*)d_ws;

    float* qT  = ws;                               // -> qpk -> wopl
    float* kT  = ws + (size_t)1 * 4194304;         // -> kpk
    float* vT  = ws + (size_t)2 * 4194304;         // -> vpk
    float* qiT = ws + (size_t)3 * 4194304;         // w-planes -> qipk
    float* kiT = ws + (size_t)4 * 4194304;         // -> kipk
    float* att = ws + (size_t)5 * 4194304;         // x-planes -> att-planes
    float2* tw   = (float2*)(ws + (size_t)6 * 4194304);
    float2* filt = (float2*)(ws + (size_t)6 * 4194304 + 2048);

    _Float16* wpl   = (_Float16*)qiT;    // 3 x (2MB hi + 2MB lo) = 12MB
    _Float16* xpl   = (_Float16*)att;    // 8MB hi + 8MB lo = 16MB
    _Float16* attpl = (_Float16*)att;    // 8MB hi + 8MB lo (after xpl dead)
    _Float16* wopl  = (_Float16*)qT;     // 2MB hi + 2MB lo (after flash)

    k_init_tables<<<8, 256, 0, stream>>>(tw, filt, fd, alpha, fas);
    k_prep_wpl3<<<dim3(16, 16, 3), 256, 0, stream>>>(wq, wk, wv, wpl);
    k_prep_xpl<<<dim3(64, 16), 256, 0, stream>>>(x, xpl);
    k_gemm_qkv<<<dim3(8, 32, 3), 256, 0, stream>>>(xpl, wpl, bq, bk, bv,
                                                   qT, kT, vT);
    k_fft_filter<<<3072, 256, 0, stream>>>(qT, kT, vT, qiT, kiT, tw, filt);
    k_flash<<<256, 512, 0, stream>>>((const unsigned*)qT, (const unsigned*)qiT,
                                     (const unsigned*)kT, (const unsigned*)kiT,
                                     (const unsigned*)vT, attpl);
    k_prep_wpl1<<<dim3(16, 16), 256, 0, stream>>>(wo, wopl);
    k_gemm_out<<<dim3(32, 8), 256, 0, stream>>>(attpl, wopl, bo, out);
    k_norm<<<4096, 256, 0, stream>>>(x, out, en);
}